// Round 1
// 482.356 us; speedup vs baseline: 1.0955x; 1.0955x over previous
//
#include <hip/hip_runtime.h>

typedef unsigned short u16;
typedef unsigned int   u32;
typedef __attribute__((ext_vector_type(8))) short s16x8;   // 8 x bf16 payload (4 VGPRs)
typedef __attribute__((ext_vector_type(4))) float f32x4;   // MFMA accumulator / f32 quad
typedef __attribute__((ext_vector_type(16))) float f32x16; // 32x32 MFMA accumulator

#define MFMA16(a, b, c) __builtin_amdgcn_mfma_f32_16x16x32_bf16((a), (b), (c), 0, 0, 0)
#define MFMA32(a, b, c) __builtin_amdgcn_mfma_f32_32x32x16_bf16((a), (b), (c), 0, 0, 0)

// ws layout (bf16 elements): [PW_bf16: 1,048,576][Qc|Kc|Vc: 3*segE][AO if HG<16]
// Qc,Kc: [p][2048 t][64 d].  Vc: TRANSPOSED [p][64 d][2048 t]  (for k_attn B-frags)
#define PWOFF 1048576ull

__device__ __forceinline__ u16 f2b(float f) {
  union { float f; unsigned i; } x; x.f = f;
  unsigned r = x.i + 0x7FFFu + ((x.i >> 16) & 1u);
  return (u16)(r >> 16);
}
__device__ __forceinline__ s16x8 cvt8(const float* __restrict__ p) {
  f32x4 a = *(const f32x4*)p;
  f32x4 b = *(const f32x4*)(p + 4);
  s16x8 o;
#pragma unroll
  for (int j = 0; j < 4; ++j) { o[j] = (short)f2b(a[j]); o[4 + j] = (short)f2b(b[j]); }
  return o;
}

__device__ __forceinline__ u32 cvtpk_bf16(float a, float b) {
  u32 r;
  asm("v_cvt_pk_bf16_f32 %0, %1, %2" : "=v"(r) : "v"(a), "v"(b));
  return r;
}
__device__ __forceinline__ void plswap(u32& a, u32& b) {
#if __has_builtin(__builtin_amdgcn_permlane32_swap)
  auto r = __builtin_amdgcn_permlane32_swap(a, b, false, false);
  a = r[0]; b = r[1];
#else
  asm volatile("v_permlane32_swap_b32 %0, %1" : "+v"(a), "+v"(b));
#endif
}
// Build PV A-fragment (contraction slice of 16 k) from 8 packed f32 P values.
// Lane holds P[k = crow(r,hi)] with crow = (r&3)+8*(r>>2)+4*hi; the swap gives
// lanes l<->l+32 each other's missing half: frag words (k0k1)(k2k3)(k4k5)(k6k7).
__device__ __forceinline__ s16x8 mk_pa(float e0, float e1, float e2, float e3,
                                       float e4, float e5, float e6, float e7) {
  u32 a0 = cvtpk_bf16(e0, e1), b0 = cvtpk_bf16(e4, e5);
  u32 a1 = cvtpk_bf16(e2, e3), b1 = cvtpk_bf16(e6, e7);
  plswap(a0, b0);
  plswap(a1, b1);
  union { u32 u[4]; s16x8 v; } x;
  x.u[0] = a0; x.u[1] = a1; x.u[2] = b0; x.u[3] = b1;
  return x.v;
}

// ---------------------------------------------------------------------------
// Beacon (only if ws too small for any path): fill d_out with 3000+wsMB.
// ---------------------------------------------------------------------------
__global__ void k_beacon(float* __restrict__ Out, unsigned long long ws_size) {
  float V = 3000.0f + fminf((float)(ws_size >> 20), 999.0f);
  size_t i = ((size_t)blockIdx.x * 256 + threadIdx.x) * 8;
#pragma unroll
  for (int j = 0; j < 8; ++j) Out[i + j] = V;
}

// ---------------------------------------------------------------------------
// proj_w fp32 [1024,1024] -> bf16 at ws[0..1048576)
// ---------------------------------------------------------------------------
__global__ void k_convert_pw(const float* __restrict__ PW, u16* __restrict__ ws) {
  size_t i = ((size_t)blockIdx.x * 256 + threadIdx.x) * 8;
  *(s16x8*)(ws + i) = cvt8(PW + i);
}

// ---------------------------------------------------------------------------
// Kernel 1: chunked QKV GEMM + bias + RoPE. fp32 in, bf16 MFMA, wide stores.
// grid ((3*HG)/2, 64), 256 thr. Writes Qc,Kc (rope'd) [p][t][64];
// Vc TRANSPOSED [p][64 d][2048 t] so k_attn can read V^T fragments directly.
// ---------------------------------------------------------------------------
__global__ __launch_bounds__(256) void k_qkv_rope(
    const float* __restrict__ X, const float* __restrict__ W,
    const float* __restrict__ Bias, u16* __restrict__ ws,
    int h0, int lgHB, int lgHG)
{
  __shared__ __align__(16) u16 smem[18432];   // As[4096] Bs[4096] | epilogue 4x(64x72)
  u16* As = smem;
  u16* Bs = smem + 4096;

  const size_t segE = 524288ull << lgHG;
  u16* Qc = ws + PWOFF;
  u16* Kc = Qc + segE;
  u16* Vc = Kc + segE;

  const int tid = threadIdx.x;
  const int w = tid >> 6, lane = tid & 63, quad = lane >> 4, l16 = lane & 15;
  const int wr = w >> 1, wc = w & 1;
  const int m0 = blockIdx.y * 128, n0 = blockIdx.x * 128;
  const int HB = 1 << lgHB;

  const f32x4 z4 = {0.f, 0.f, 0.f, 0.f};
  f32x4 acc[4][4];
#pragma unroll
  for (int i = 0; i < 4; ++i)
#pragma unroll
    for (int j = 0; j < 4; ++j) acc[i][j] = z4;

  const int srow = tid >> 2;
  const int scol = (tid & 3) * 8;
  const int nlogA = n0 + srow, nlogB = nlogA + 64;
  const int wrowA = (nlogA >> lgHB) * 1024 + (h0 + ((nlogA & (HB - 1)) >> 6)) * 64 + (nlogA & 63);
  const int wrowB = (nlogB >> lgHB) * 1024 + (h0 + ((nlogB & (HB - 1)) >> 6)) * 64 + (nlogB & 63);
  const float* Ag  = X + (size_t)(m0 + srow) * 1024 + scol;
  const float* BgA = W + (size_t)wrowA * 1024 + scol;
  const float* BgB = W + (size_t)wrowB * 1024 + scol;

  for (int k0 = 0; k0 < 1024; k0 += 32) {
    s16x8 a0 = cvt8(Ag + k0);
    s16x8 a1 = cvt8(Ag + (size_t)64 * 1024 + k0);
    s16x8 b0 = cvt8(BgA + k0);
    s16x8 b1 = cvt8(BgB + k0);
    __syncthreads();
    *(s16x8*)&As[srow * 32 + scol]        = a0;
    *(s16x8*)&As[(srow + 64) * 32 + scol] = a1;
    *(s16x8*)&Bs[srow * 32 + scol]        = b0;
    *(s16x8*)&Bs[(srow + 64) * 32 + scol] = b1;
    __syncthreads();
    s16x8 af[4], bf[4];
#pragma unroll
    for (int i = 0; i < 4; ++i)
      af[i] = *(const s16x8*)&As[(wr * 64 + i * 16 + l16) * 32 + quad * 8];
#pragma unroll
    for (int j = 0; j < 4; ++j)
      bf[j] = *(const s16x8*)&Bs[(wc * 64 + j * 16 + l16) * 32 + quad * 8];
#pragma unroll
    for (int i = 0; i < 4; ++i)
#pragma unroll
      for (int j = 0; j < 4; ++j)
        acc[i][j] = MFMA16(af[i], bf[j], acc[i][j]);
  }

  const int ncol = n0 + wc * 64;              // 64-aligned -> single (which,hh)
  const int which = ncol >> lgHB;             // 0=q 1=k 2=v
  const int hh = (ncol & (HB - 1)) >> 6;
  const int cb = which * 1024 + (h0 + hh) * 64;
  const int mbase = m0 + wr * 64;
  float bias[4];
#pragma unroll
  for (int j = 0; j < 4; ++j) bias[j] = Bias[cb + j * 16 + l16];

  __syncthreads();                       // all waves done with As/Bs
  u16* OSt = smem + w * 4608;            // 64 rows x 72 (stride 144B, 16B-aligned)

  if (which == 2) {
    // V: write TRANSPOSED tile OSt[d][tok] (64x72)
#pragma unroll
    for (int i = 0; i < 4; ++i)
#pragma unroll
      for (int r = 0; r < 4; ++r) {
        int tl = i * 16 + quad * 4 + r;
#pragma unroll
        for (int j = 0; j < 4; ++j)
          OSt[(j * 16 + l16) * 72 + tl] = f2b(acc[i][j][r] + bias[j]);
      }
  } else {
    const float LC = 0.1716750968f;      // log2(40)/31
    float fr0 = exp2f((float)l16 * LC);            // freq for dim l16
    float fr1 = exp2f((float)(16 + l16) * LC);     // freq for dim 16+l16
#pragma unroll
    for (int i = 0; i < 4; ++i)
#pragma unroll
      for (int r = 0; r < 4; ++r) {
        int tl = i * 16 + quad * 4 + r;
        int tok = mbase + tl;
        // revolutions = (t/2048)*freq; v_sin/v_cos take revolutions
        float ps = (float)(tok & 2047) * (1.0f / 2048.0f);
        float rv0 = ps * fr0; rv0 -= floorf(rv0);
        float rv1 = ps * fr1; rv1 -= floorf(rv1);
        float s0 = __builtin_amdgcn_sinf(rv0), c0 = __builtin_amdgcn_cosf(rv0);
        float s1 = __builtin_amdgcn_sinf(rv1), c1 = __builtin_amdgcn_cosf(rv1);
        float x10 = acc[i][0][r] + bias[0], x11 = acc[i][1][r] + bias[1];
        float x20 = acc[i][2][r] + bias[2], x21 = acc[i][3][r] + bias[3];
        OSt[tl * 72 + l16]      = f2b(x10 * c0 - x20 * s0);
        OSt[tl * 72 + 16 + l16] = f2b(x11 * c1 - x21 * s1);
        OSt[tl * 72 + 32 + l16] = f2b(x10 * s0 + x20 * c0);
        OSt[tl * 72 + 48 + l16] = f2b(x11 * s1 + x21 * c1);
      }
  }
  // same-wave LDS ordering; wide contiguous stores (16B/lane)
  if (which == 2) {
    const int bb = mbase >> 11, tt0 = mbase & 2047;   // 64-row tile within one batch
    const int pv = (bb << lgHG) + hh;
#pragma unroll
    for (int itr = 0; itr < 8; ++itr) {
      int task = itr * 64 + lane;
      int dd = task >> 3, g = task & 7;
      *(s16x8*)&Vc[(size_t)pv * 131072 + (size_t)dd * 2048 + tt0 + g * 8] =
          *(const s16x8*)&OSt[dd * 72 + g * 8];
    }
  } else {
    u16* D = (which == 0) ? Qc : Kc;
#pragma unroll
    for (int itr = 0; itr < 8; ++itr) {
      int task = itr * 64 + lane;
      int tl = task >> 3, g = task & 7;
      int tok = mbase + tl;
      int bb = tok >> 11, tt = tok & 2047;
      int p = (bb << lgHG) + hh;
      *(s16x8*)&D[((size_t)p * 2048 + tt) * 64 + g * 8] =
          *(const s16x8*)&OSt[tl * 72 + g * 8];
    }
  }
}

// ---------------------------------------------------------------------------
// Kernel 2: flash attention, swapped-operand 32x32 MFMA, zero LDS in hot loop.
// grid (16, 4*HG), 256 thr (4 indep waves, 32 q-rows each).
//  - QK^T computed as mfma32(K_frag, Q_frag): lane owns P[k=crow(r,hi)][q=l&31]
//    -> softmax stats fully in-register (+ one shfl_xor(32)).
//  - P -> PV A-frags via v_cvt_pk_bf16_f32 + v_permlane32_swap (T12).
//  - K frags read direct from Kc[p][t][64] (L2-resident, 256KB/head).
//  - V frags read direct from TRANSPOSED Vc[p][64][2048].
//  - defer-max (THR=8 raw = 1 nat): O-rescale (needs per-crow alpha broadcast
//    through 512B LDS) only when running max grows.
//  - bijective XCD swizzle: each XCD owns P/8 heads -> 4MB KV set fits its L2.
// AO written bf16 [b*16+head][t][64] (aliases Qc when HG=16: each block reads
// only its own 128 Q rows at start, writes only those rows at the end).
// ---------------------------------------------------------------------------
__global__ __launch_bounds__(256) void k_attn(
    u16* __restrict__ ws, u16* __restrict__ AO, int h0, int lgHG)
{
  __shared__ float redL[4][32];          // per-wave alpha / inv-li broadcast

  const size_t segE = 524288ull << lgHG;
  const u16* Qg = ws + PWOFF;
  const u16* Kg = Qg + segE;
  const u16* Vg = Kg + segE;

  const int tid = threadIdx.x;
  const int w = tid >> 6, lane = tid & 63;
  const int l31 = lane & 31, hi = lane >> 5;

  // XCD swizzle: n = p_raw*16 + qt_raw; xcd = n&7 gets heads [xcd*P/8, ...)
  const int P = 4 << lgHG;
  const int n = blockIdx.y * 16 + blockIdx.x;
  const int mm = n >> 3;
  const int p  = (n & 7) * (P >> 3) + (mm >> 4);
  const int qt = mm & 15;

  const u16* Qb = Qg + (size_t)p * 131072;
  const u16* Kb = Kg + (size_t)p * 131072;
  const u16* Vb = Vg + (size_t)p * 131072;
  const int q0 = qt * 128 + w * 32;

  // Q fragments (B-operand): lane holds Q[q0+l31][ks*16 + hi*8 .. +7]
  s16x8 qf[4];
#pragma unroll
  for (int ks = 0; ks < 4; ++ks)
    qf[ks] = *(const s16x8*)&Qb[(size_t)(q0 + l31) * 64 + ks * 16 + hi * 8];

  f32x16 o0, o1;                         // O[q=crow(r,hi)][d=l31 (+32)]
#pragma unroll
  for (int r = 0; r < 16; ++r) { o0[r] = 0.f; o1[r] = 0.f; }
  float m_r = -1e30f, li = 0.f;
  const float C = 0.1803368801f;         // 0.125 * log2(e)

  for (int kt = 0; kt < 32; ++kt) {
    const int kbase = kt * 64;
    // K frags (A-operand, rows=k): lane holds K[kbase+kb*32+l31][ks*16+hi*8..]
    // V frags (B-operand, rows=d): lane holds V^T[db*32+l31][kbase+ks*16+hi*8..]
    s16x8 kfA[4], kfB[4], vfA[4], vfB[4];
#pragma unroll
    for (int ks = 0; ks < 4; ++ks) {
      const int dof = ks * 16 + hi * 8;
      kfA[ks] = *(const s16x8*)&Kb[(size_t)(kbase + l31) * 64 + dof];
      kfB[ks] = *(const s16x8*)&Kb[(size_t)(kbase + 32 + l31) * 64 + dof];
      vfA[ks] = *(const s16x8*)&Vb[(size_t)l31 * 2048 + kbase + dof];
      vfB[ks] = *(const s16x8*)&Vb[(size_t)(32 + l31) * 2048 + kbase + dof];
    }

    // swapped QK^T: C[row = k-local = crow(r,hi)][col = q = l31]
    f32x16 s0, s1;
#pragma unroll
    for (int r = 0; r < 16; ++r) { s0[r] = 0.f; s1[r] = 0.f; }
#pragma unroll
    for (int ks = 0; ks < 4; ++ks) {
      s0 = MFMA32(kfA[ks], qf[ks], s0);
      s1 = MFMA32(kfB[ks], qf[ks], s1);
    }

    // row max: lane owns 32 of 64 k for its q; partner (l^32) owns the rest
    float mx = fmaxf(s0[0], s1[0]);
#pragma unroll
    for (int r = 1; r < 16; ++r) mx = fmaxf(mx, fmaxf(s0[r], s1[r]));
    mx = fmaxf(mx, __shfl_xor(mx, 32));

    // defer-max: rescale O only when max grew past THR (wave-uniform branch)
    if (!__all(mx - m_r <= 8.0f)) {
      float mnew = fmaxf(m_r, mx);
      float al = exp2f((m_r - mnew) * C);
      m_r = mnew;
      li *= al;
      if (hi == 0) redL[w][l31] = al;    // alpha[q] at q=l31
      f32x4 a0 = *(const f32x4*)&redL[w][hi * 4];       // crow rows 8g+4hi+e
      f32x4 a1 = *(const f32x4*)&redL[w][8 + hi * 4];
      f32x4 a2 = *(const f32x4*)&redL[w][16 + hi * 4];
      f32x4 a3 = *(const f32x4*)&redL[w][24 + hi * 4];
#pragma unroll
      for (int e = 0; e < 4; ++e) {
        o0[e]      *= a0[e];  o1[e]      *= a0[e];
        o0[4 + e]  *= a1[e];  o1[4 + e]  *= a1[e];
        o0[8 + e]  *= a2[e];  o1[8 + e]  *= a2[e];
        o0[12 + e] *= a3[e];  o1[12 + e] *= a3[e];
      }
    }

    const float mC = m_r * C;
    float pv0[16], pv1[16];
    float sum = 0.f;
#pragma unroll
    for (int r = 0; r < 16; ++r) {
      pv0[r] = exp2f(s0[r] * C - mC);
      pv1[r] = exp2f(s1[r] * C - mC);
      sum += pv0[r] + pv1[r];
    }
    sum += __shfl_xor(sum, 32);
    li += sum;

    // P -> A-frags (k slices of 16): regs 0..7 = k 0..15, regs 8..15 = k 16..31
    s16x8 pa0 = mk_pa(pv0[0], pv0[1], pv0[2],  pv0[3],  pv0[4],  pv0[5],  pv0[6],  pv0[7]);
    s16x8 pa1 = mk_pa(pv0[8], pv0[9], pv0[10], pv0[11], pv0[12], pv0[13], pv0[14], pv0[15]);
    s16x8 pa2 = mk_pa(pv1[0], pv1[1], pv1[2],  pv1[3],  pv1[4],  pv1[5],  pv1[6],  pv1[7]);
    s16x8 pa3 = mk_pa(pv1[8], pv1[9], pv1[10], pv1[11], pv1[12], pv1[13], pv1[14], pv1[15]);

    o0 = MFMA32(pa0, vfA[0], o0);  o1 = MFMA32(pa0, vfB[0], o1);
    o0 = MFMA32(pa1, vfA[1], o0);  o1 = MFMA32(pa1, vfB[1], o1);
    o0 = MFMA32(pa2, vfA[2], o0);  o1 = MFMA32(pa2, vfB[2], o1);
    o0 = MFMA32(pa3, vfA[3], o0);  o1 = MFMA32(pa3, vfB[3], o1);
  }

  // epilogue: broadcast 1/li per q, scale, store bf16
  if (hi == 0) redL[w][l31] = 1.0f / li;
  f32x4 i0 = *(const f32x4*)&redL[w][hi * 4];
  f32x4 i1 = *(const f32x4*)&redL[w][8 + hi * 4];
  f32x4 i2 = *(const f32x4*)&redL[w][16 + hi * 4];
  f32x4 i3 = *(const f32x4*)&redL[w][24 + hi * 4];

  const int p_glob = (p >> lgHG) * 16 + h0 + (p & ((1 << lgHG) - 1));
  u16* Ab = AO + (size_t)p_glob * 131072 + (size_t)q0 * 64;
#pragma unroll
  for (int g = 0; g < 4; ++g) {
    const f32x4 iv = (g == 0) ? i0 : (g == 1) ? i1 : (g == 2) ? i2 : i3;
#pragma unroll
    for (int e = 0; e < 4; ++e) {
      int row = g * 8 + hi * 4 + e;      // crow(r,hi), r = g*4+e
      Ab[(size_t)row * 64 + l31]      = f2b(o0[g * 4 + e] * iv[e]);
      Ab[(size_t)row * 64 + 32 + l31] = f2b(o1[g * 4 + e] * iv[e]);
    }
  }
}

// ---------------------------------------------------------------------------
// Kernel 3: Out(fp32) = AO @ proj_w^T + proj_b. AO bf16 at [b*16+h][t][64],
// PW bf16 from ws. grid (8, 64), 256 thr. fp32 stores staged wide via LDS.
// ---------------------------------------------------------------------------
__global__ __launch_bounds__(256) void k_proj(
    const u16* __restrict__ AO, const u16* __restrict__ W,
    const float* __restrict__ Bias, float* __restrict__ Out)
{
  __shared__ __align__(16) u16 As[128 * 32];
  __shared__ __align__(16) u16 Bs[128 * 32];
  __shared__ __align__(16) float OStage[4 * 32 * 64];   // 32 KB
  const int tid = threadIdx.x;
  const int w = tid >> 6, lane = tid & 63, quad = lane >> 4, l16 = lane & 15;
  const int wr = w >> 1, wc = w & 1;
  const int m0 = blockIdx.y * 128, n0 = blockIdx.x * 128;

  const f32x4 z4 = {0.f, 0.f, 0.f, 0.f};
  f32x4 acc[4][4];
#pragma unroll
  for (int i = 0; i < 4; ++i)
#pragma unroll
    for (int j = 0; j < 4; ++j) acc[i][j] = z4;

  const int srow = tid >> 2;
  const int scol = (tid & 3) * 8;
  const int tok = m0 + srow;                  // tile never crosses batch bdry
  const int bb = tok >> 11, tt = tok & 2047;
  const u16* Abase = AO + (size_t)bb * 2097152 + (size_t)tt * 64;
  const u16* Bg = W + (size_t)(n0 + srow) * 1024 + scol;

  for (int k0 = 0; k0 < 1024; k0 += 32) {
    const int c0 = k0 + scol;                 // head*64 + off (within one head)
    const size_t aoff = (size_t)(c0 >> 6) * 131072 + (size_t)(c0 & 63);
    s16x8 a0 = *(const s16x8*)(Abase + aoff);
    s16x8 a1 = *(const s16x8*)(Abase + 4096 + aoff);   // tok+64 -> tt+64
    s16x8 b0 = *(const s16x8*)(Bg + k0);
    s16x8 b1 = *(const s16x8*)(Bg + (size_t)64 * 1024 + k0);
    __syncthreads();
    *(s16x8*)&As[srow * 32 + scol]        = a0;
    *(s16x8*)&As[(srow + 64) * 32 + scol] = a1;
    *(s16x8*)&Bs[srow * 32 + scol]        = b0;
    *(s16x8*)&Bs[(srow + 64) * 32 + scol] = b1;
    __syncthreads();
    s16x8 af[4], bf[4];
#pragma unroll
    for (int i = 0; i < 4; ++i)
      af[i] = *(const s16x8*)&As[(wr * 64 + i * 16 + l16) * 32 + quad * 8];
#pragma unroll
    for (int j = 0; j < 4; ++j)
      bf[j] = *(const s16x8*)&Bs[(wc * 64 + j * 16 + l16) * 32 + quad * 8];
#pragma unroll
    for (int i = 0; i < 4; ++i)
#pragma unroll
      for (int j = 0; j < 4; ++j)
        acc[i][j] = MFMA16(af[i], bf[j], acc[i][j]);
  }

  const int ncol = n0 + wc * 64;
  float bias[4];
#pragma unroll
  for (int j = 0; j < 4; ++j) bias[j] = Bias[ncol + j * 16 + l16];

  float* OS = OStage + w * 2048;        // 32 rows x 64 cols fp32
#pragma unroll
  for (int h = 0; h < 2; ++h) {
#pragma unroll
    for (int ii = 0; ii < 2; ++ii) {
      int i = h * 2 + ii;
#pragma unroll
      for (int j = 0; j < 4; ++j)
#pragma unroll
        for (int r = 0; r < 4; ++r) {
          int tl = ii * 16 + quad * 4 + r;
          OS[tl * 64 + j * 16 + l16] = acc[i][j][r] + bias[j];
        }
    }
    // same-wave ordering; wide stores: 16B/lane, 256B per 16 lanes
#pragma unroll
    for (int itr = 0; itr < 8; ++itr) {
      int task = itr * 64 + lane;
      int tl = task >> 4, g = task & 15;
      int row = m0 + wr * 64 + h * 32 + tl;
      *(f32x4*)&Out[(size_t)row * 1024 + ncol + g * 4] =
          *(const f32x4*)&OS[tl * 64 + g * 4];
    }
  }
}

// ---------------------------------------------------------------------------
extern "C" void kernel_launch(void* const* d_in, const int* in_sizes, int n_in,
                              void* d_out, int out_size, void* d_ws, size_t ws_size,
                              hipStream_t stream) {
  const float* X    = (const float*)d_in[0];   // [4,2048,1024] fp32
  const float* QKVW = (const float*)d_in[1];   // [3072,1024]
  const float* QKVB = (const float*)d_in[2];   // [3072]
  const float* PW   = (const float*)d_in[3];   // [1024,1024]
  const float* PB   = (const float*)d_in[4];   // [1024]
  float* Out = (float*)d_out;                  // [4,2048,1024] fp32
  u16* ws = (u16*)d_ws;

  // ws (bytes): HG16: 2*(PWOFF+3*segE)=52.4MB (AO aliases Qc);
  // HG<16: + dedicated AO (16.8MB).
  int HG, lgHG, ok = 1;
  if      (ws_size >= 52428800ull) { HG = 16; lgHG = 4; }
  else if (ws_size >= 44040192ull) { HG = 8;  lgHG = 3; }
  else if (ws_size >= 31457280ull) { HG = 4;  lgHG = 2; }
  else if (ws_size >= 25165824ull) { HG = 2;  lgHG = 1; }
  else                             { HG = 2;  lgHG = 1; ok = 0; }

  if (!ok) {
    k_beacon<<<dim3(4096), 256, 0, stream>>>(Out, (unsigned long long)ws_size);
    return;
  }

  const size_t segE = 524288ull << lgHG;
  u16* Qc = ws + PWOFF;
  u16* AO = (HG == 16) ? Qc : (Qc + 3 * segE);
  const int lgHB = lgHG + 6;

  k_convert_pw<<<dim3(512), 256, 0, stream>>>(PW, ws);

  const int chunks = 16 / HG;
  for (int c = 0; c < chunks; ++c) {
    int h0 = c * HG;
    k_qkv_rope<<<dim3((3 * HG) / 2, 64), 256, 0, stream>>>(
        X, QKVW, QKVB, ws, h0, lgHB, lgHG);
    k_attn<<<dim3(16, 4 * HG), 256, 0, stream>>>(ws, AO, h0, lgHG);
  }
  k_proj<<<dim3(8, 64), 256, 0, stream>>>(AO, ws, PB, Out);
}

// Round 2
// 400.570 us; speedup vs baseline: 1.3192x; 1.2042x over previous
//
#include <hip/hip_runtime.h>

typedef unsigned short u16;
typedef unsigned int   u32;
typedef __attribute__((ext_vector_type(8))) short s16x8;   // 8 x bf16 payload (4 VGPRs)
typedef __attribute__((ext_vector_type(4))) float f32x4;   // MFMA accumulator / f32 quad
typedef __attribute__((ext_vector_type(16))) float f32x16; // 32x32 MFMA accumulator

#define MFMA16(a, b, c) __builtin_amdgcn_mfma_f32_16x16x32_bf16((a), (b), (c), 0, 0, 0)
#define MFMA32(a, b, c) __builtin_amdgcn_mfma_f32_32x32x16_bf16((a), (b), (c), 0, 0, 0)

// ws layout (bf16 elements): [PW_bf16: 1,048,576][Qc|Kc|Vc: 3*segE][AO if HG<16]
// FRAGMENT-MAJOR layouts (so k_attn hot-loop loads are contiguous 1KB/wave):
//  Qc: [p][qt32 (64)][ks (4)][lane (64)][8]   qt32 = 32-token q tile
//  Kc: [p][kt (32)][ks*2+kb (8)][lane (64)][8]
//  Vc: [p][kt (32)][ks*2+db (8)][lane (64)][8]
// frag element semantics documented at the producer epilogue below.
#define PWOFF 1048576ull

__device__ __forceinline__ u16 f2b(float f) {
  union { float f; unsigned i; } x; x.f = f;
  unsigned r = x.i + 0x7FFFu + ((x.i >> 16) & 1u);
  return (u16)(r >> 16);
}
__device__ __forceinline__ s16x8 cvt8(const float* __restrict__ p) {
  f32x4 a = *(const f32x4*)p;
  f32x4 b = *(const f32x4*)(p + 4);
  s16x8 o;
#pragma unroll
  for (int j = 0; j < 4; ++j) { o[j] = (short)f2b(a[j]); o[4 + j] = (short)f2b(b[j]); }
  return o;
}

__device__ __forceinline__ u32 cvtpk_bf16(float a, float b) {
  u32 r;
  asm("v_cvt_pk_bf16_f32 %0, %1, %2" : "=v"(r) : "v"(a), "v"(b));
  return r;
}
__device__ __forceinline__ void plswap(u32& a, u32& b) {
#if __has_builtin(__builtin_amdgcn_permlane32_swap)
  auto r = __builtin_amdgcn_permlane32_swap(a, b, false, false);
  a = r[0]; b = r[1];
#else
  asm volatile("v_permlane32_swap_b32 %0, %1" : "+v"(a), "+v"(b));
#endif
}
// Cross-half (lane <-> lane^32) partner fetch, VALU-only (no DS op in the
// softmax critical path). After plswap: a' = [a.lo|b.lo], b' = [a.hi|b.hi];
// partner of lane l is in b' for l<32 and in a' for l>=32.
__device__ __forceinline__ float pair32(float x, int hi) {
  union { float f; u32 u; } a, b;
  a.f = x; b.f = x;
  plswap(a.u, b.u);
  return hi ? a.f : b.f;
}
// Build PV A-fragment (contraction slice of 16 k) from 8 packed f32 P values.
// Lane holds P[k = crow(r,hi)] with crow = (r&3)+8*(r>>2)+4*hi; the swap gives
// lanes l<->l+32 each other's missing half: frag words (k0k1)(k2k3)(k4k5)(k6k7).
__device__ __forceinline__ s16x8 mk_pa(float e0, float e1, float e2, float e3,
                                       float e4, float e5, float e6, float e7) {
  u32 a0 = cvtpk_bf16(e0, e1), b0 = cvtpk_bf16(e4, e5);
  u32 a1 = cvtpk_bf16(e2, e3), b1 = cvtpk_bf16(e6, e7);
  plswap(a0, b0);
  plswap(a1, b1);
  union { u32 u[4]; s16x8 v; } x;
  x.u[0] = a0; x.u[1] = a1; x.u[2] = b0; x.u[3] = b1;
  return x.v;
}

// ---------------------------------------------------------------------------
// Beacon (only if ws too small for any path): fill d_out with 3000+wsMB.
// ---------------------------------------------------------------------------
__global__ void k_beacon(float* __restrict__ Out, unsigned long long ws_size) {
  float V = 3000.0f + fminf((float)(ws_size >> 20), 999.0f);
  size_t i = ((size_t)blockIdx.x * 256 + threadIdx.x) * 8;
#pragma unroll
  for (int j = 0; j < 8; ++j) Out[i + j] = V;
}

// ---------------------------------------------------------------------------
// proj_w fp32 [1024,1024] -> bf16 at ws[0..1048576)
// ---------------------------------------------------------------------------
__global__ void k_convert_pw(const float* __restrict__ PW, u16* __restrict__ ws) {
  size_t i = ((size_t)blockIdx.x * 256 + threadIdx.x) * 8;
  *(s16x8*)(ws + i) = cvt8(PW + i);
}

// ---------------------------------------------------------------------------
// Kernel 1: chunked QKV GEMM + bias + RoPE. fp32 in, bf16 MFMA, wide stores.
// grid ((3*HG)/2, 64), 256 thr. Writes Qc/Kc/Vc in FRAGMENT-MAJOR layout:
// each wave owns a full 64-token x 64-d tile of one head (tokens 64-aligned,
// never crossing a batch boundary), stages it in LDS (rope'd rows for Q/K,
// transposed for V), then stores the exact k_attn MFMA fragments as
// contiguous 1KB wave writes.
// ---------------------------------------------------------------------------
__global__ __launch_bounds__(256) void k_qkv_rope(
    const float* __restrict__ X, const float* __restrict__ W,
    const float* __restrict__ Bias, u16* __restrict__ ws,
    int h0, int lgHB, int lgHG)
{
  __shared__ __align__(16) u16 smem[18432];   // As[4096] Bs[4096] | epilogue 4x(64x72)
  u16* As = smem;
  u16* Bs = smem + 4096;

  const size_t segE = 524288ull << lgHG;
  u16* Qc = ws + PWOFF;
  u16* Kc = Qc + segE;
  u16* Vc = Kc + segE;

  const int tid = threadIdx.x;
  const int w = tid >> 6, lane = tid & 63, quad = lane >> 4, l16 = lane & 15;
  const int l31 = lane & 31, hi = lane >> 5;
  const int wr = w >> 1, wc = w & 1;
  const int m0 = blockIdx.y * 128, n0 = blockIdx.x * 128;
  const int HB = 1 << lgHB;

  const f32x4 z4 = {0.f, 0.f, 0.f, 0.f};
  f32x4 acc[4][4];
#pragma unroll
  for (int i = 0; i < 4; ++i)
#pragma unroll
    for (int j = 0; j < 4; ++j) acc[i][j] = z4;

  const int srow = tid >> 2;
  const int scol = (tid & 3) * 8;
  const int nlogA = n0 + srow, nlogB = nlogA + 64;
  const int wrowA = (nlogA >> lgHB) * 1024 + (h0 + ((nlogA & (HB - 1)) >> 6)) * 64 + (nlogA & 63);
  const int wrowB = (nlogB >> lgHB) * 1024 + (h0 + ((nlogB & (HB - 1)) >> 6)) * 64 + (nlogB & 63);
  const float* Ag  = X + (size_t)(m0 + srow) * 1024 + scol;
  const float* BgA = W + (size_t)wrowA * 1024 + scol;
  const float* BgB = W + (size_t)wrowB * 1024 + scol;

  for (int k0 = 0; k0 < 1024; k0 += 32) {
    s16x8 a0 = cvt8(Ag + k0);
    s16x8 a1 = cvt8(Ag + (size_t)64 * 1024 + k0);
    s16x8 b0 = cvt8(BgA + k0);
    s16x8 b1 = cvt8(BgB + k0);
    __syncthreads();
    *(s16x8*)&As[srow * 32 + scol]        = a0;
    *(s16x8*)&As[(srow + 64) * 32 + scol] = a1;
    *(s16x8*)&Bs[srow * 32 + scol]        = b0;
    *(s16x8*)&Bs[(srow + 64) * 32 + scol] = b1;
    __syncthreads();
    s16x8 af[4], bf[4];
#pragma unroll
    for (int i = 0; i < 4; ++i)
      af[i] = *(const s16x8*)&As[(wr * 64 + i * 16 + l16) * 32 + quad * 8];
#pragma unroll
    for (int j = 0; j < 4; ++j)
      bf[j] = *(const s16x8*)&Bs[(wc * 64 + j * 16 + l16) * 32 + quad * 8];
#pragma unroll
    for (int i = 0; i < 4; ++i)
#pragma unroll
      for (int j = 0; j < 4; ++j)
        acc[i][j] = MFMA16(af[i], bf[j], acc[i][j]);
  }

  const int ncol = n0 + wc * 64;              // 64-aligned -> single (which,hh)
  const int which = ncol >> lgHB;             // 0=q 1=k 2=v
  const int hh = (ncol & (HB - 1)) >> 6;
  const int cb = which * 1024 + (h0 + hh) * 64;
  const int mbase = m0 + wr * 64;
  float bias[4];
#pragma unroll
  for (int j = 0; j < 4; ++j) bias[j] = Bias[cb + j * 16 + l16];

  __syncthreads();                       // all waves done with As/Bs
  u16* OSt = smem + w * 4608;            // 64 rows x 72 (stride 144B, 16B-aligned)

  if (which == 2) {
    // V: stage TRANSPOSED tile OSt[d][tok_local] (64x72)
#pragma unroll
    for (int i = 0; i < 4; ++i)
#pragma unroll
      for (int r = 0; r < 4; ++r) {
        int tl = i * 16 + quad * 4 + r;
#pragma unroll
        for (int j = 0; j < 4; ++j)
          OSt[(j * 16 + l16) * 72 + tl] = f2b(acc[i][j][r] + bias[j]);
      }
  } else {
    const float LC = 0.1716750968f;      // log2(40)/31
    float fr0 = exp2f((float)l16 * LC);            // freq for dim l16
    float fr1 = exp2f((float)(16 + l16) * LC);     // freq for dim 16+l16
#pragma unroll
    for (int i = 0; i < 4; ++i)
#pragma unroll
      for (int r = 0; r < 4; ++r) {
        int tl = i * 16 + quad * 4 + r;
        int tok = mbase + tl;
        // revolutions = (t/2048)*freq; v_sin/v_cos take revolutions
        float ps = (float)(tok & 2047) * (1.0f / 2048.0f);
        float rv0 = ps * fr0; rv0 -= floorf(rv0);
        float rv1 = ps * fr1; rv1 -= floorf(rv1);
        float s0 = __builtin_amdgcn_sinf(rv0), c0 = __builtin_amdgcn_cosf(rv0);
        float s1 = __builtin_amdgcn_sinf(rv1), c1 = __builtin_amdgcn_cosf(rv1);
        float x10 = acc[i][0][r] + bias[0], x11 = acc[i][1][r] + bias[1];
        float x20 = acc[i][2][r] + bias[2], x21 = acc[i][3][r] + bias[3];
        OSt[tl * 72 + l16]      = f2b(x10 * c0 - x20 * s0);
        OSt[tl * 72 + 16 + l16] = f2b(x11 * c1 - x21 * s1);
        OSt[tl * 72 + 32 + l16] = f2b(x10 * s0 + x20 * c0);
        OSt[tl * 72 + 48 + l16] = f2b(x11 * s1 + x21 * c1);
      }
  }
  // fragment-major stores: same-wave LDS ordering; 16B/lane, 1KB/wave-instr
  const int bb = mbase >> 11, tt0 = mbase & 2047;
  const int pp = (bb << lgHG) + hh;
  if (which == 2) {
    // Vc frag (kt, fi=ks*2+db): lane holds V^T[d=db*32+l31][kt*64+ks*16+hi*8+j]
    u16* D = Vc + ((size_t)pp * 32 + (tt0 >> 6)) * 4096;
#pragma unroll
    for (int fi = 0; fi < 8; ++fi) {
      int ks = fi >> 1, db = fi & 1;
      *(s16x8*)&D[fi * 512 + lane * 8] =
          *(const s16x8*)&OSt[(db * 32 + l31) * 72 + ks * 16 + hi * 8];
    }
  } else if (which == 1) {
    // Kc frag (kt, fi=ks*2+kb): lane holds K[kt*64+kb*32+l31][ks*16+hi*8+j]
    u16* D = Kc + ((size_t)pp * 32 + (tt0 >> 6)) * 4096;
#pragma unroll
    for (int fi = 0; fi < 8; ++fi) {
      int ks = fi >> 1, kb = fi & 1;
      *(s16x8*)&D[fi * 512 + lane * 8] =
          *(const s16x8*)&OSt[(kb * 32 + l31) * 72 + ks * 16 + hi * 8];
    }
  } else {
    // Qc frag (qt32, ks): lane holds Q[qt32*32+l31][ks*16+hi*8+j]
    u16* D = Qc + ((size_t)pp * 64 + (tt0 >> 5)) * 2048;
#pragma unroll
    for (int fi = 0; fi < 8; ++fi) {
      int qh = fi >> 2, ks = fi & 3;
      *(s16x8*)&D[(size_t)qh * 2048 + ks * 512 + lane * 8] =
          *(const s16x8*)&OSt[(qh * 32 + l31) * 72 + ks * 16 + hi * 8];
    }
  }
}

// ---------------------------------------------------------------------------
// Kernel 2: flash attention, swapped-operand 32x32 MFMA, zero LDS in hot loop,
// ALL hot-loop global loads fragment-major (contiguous 1KB per wave instr).
// grid (16, 4*HG), 256 thr (4 indep waves, 32 q-rows each).
//  - QK^T computed as mfma32(K_frag, Q_frag): lane owns P[k=crow(r,hi)][q=l&31]
//  - softmax stats in-register; cross-half reduce via permlane32 (VALU-only)
//  - P -> PV A-frags via v_cvt_pk_bf16_f32 + v_permlane32_swap (T12)
//  - defer-max (THR=8 raw): O-rescale only when running max grows
//  - bijective XCD swizzle: each XCD owns P/8 heads -> 4MB KV set in its L2
// AO written bf16 [b*16+head][t][64] (aliases Qc when HG=16: each wave reads
// its own Q-frag window first, then writes only that window).
// ---------------------------------------------------------------------------
__global__ __launch_bounds__(256) void k_attn(
    u16* __restrict__ ws, u16* __restrict__ AO, int h0, int lgHG)
{
  __shared__ float redL[4][32];          // per-wave alpha / inv-li broadcast

  const size_t segE = 524288ull << lgHG;
  const u16* Qg = ws + PWOFF;
  const u16* Kg = Qg + segE;
  const u16* Vg = Kg + segE;

  const int tid = threadIdx.x;
  const int w = tid >> 6, lane = tid & 63;
  const int l31 = lane & 31, hi = lane >> 5;

  // XCD swizzle: n = by*16 + bx; xcd = n&7 gets heads [xcd*P/8, ...)
  const int P = 4 << lgHG;
  const int n = blockIdx.y * 16 + blockIdx.x;
  const int mm = n >> 3;
  const int p  = (n & 7) * (P >> 3) + (mm >> 4);
  const int qt = mm & 15;

  const u16* Kb = Kg + (size_t)p * 131072;
  const u16* Vb = Vg + (size_t)p * 131072;
  const int q0 = qt * 128 + w * 32;

  // Q fragments: frag-major, contiguous per wave
  const u16* Qt = Qg + (size_t)p * 131072 + (size_t)(qt * 4 + w) * 2048;
  s16x8 qf[4];
#pragma unroll
  for (int ks = 0; ks < 4; ++ks)
    qf[ks] = *(const s16x8*)&Qt[ks * 512 + lane * 8];

  f32x16 o0, o1;                         // O[q=crow(r,hi)][d=l31 (+32)]
#pragma unroll
  for (int r = 0; r < 16; ++r) { o0[r] = 0.f; o1[r] = 0.f; }
  float m_r = -1e30f, li = 0.f;
  const float C = 0.1803368801f;         // 0.125 * log2(e)

  for (int kt = 0; kt < 32; ++kt) {
    const u16* Kt = Kb + (size_t)kt * 4096;
    const u16* Vt = Vb + (size_t)kt * 4096;
    s16x8 kfA[4], kfB[4], vfA[4], vfB[4];
#pragma unroll
    for (int ks = 0; ks < 4; ++ks) {
      kfA[ks] = *(const s16x8*)&Kt[(ks * 2 + 0) * 512 + lane * 8];
      kfB[ks] = *(const s16x8*)&Kt[(ks * 2 + 1) * 512 + lane * 8];
      vfA[ks] = *(const s16x8*)&Vt[(ks * 2 + 0) * 512 + lane * 8];
      vfB[ks] = *(const s16x8*)&Vt[(ks * 2 + 1) * 512 + lane * 8];
    }

    // swapped QK^T: C[row = k-local = crow(r,hi)][col = q = l31]
    f32x16 s0, s1;
#pragma unroll
    for (int r = 0; r < 16; ++r) { s0[r] = 0.f; s1[r] = 0.f; }
#pragma unroll
    for (int ks = 0; ks < 4; ++ks) {
      s0 = MFMA32(kfA[ks], qf[ks], s0);
      s1 = MFMA32(kfB[ks], qf[ks], s1);
    }

    // row max: lane owns 32 of 64 k for its q; partner (l^32) owns the rest
    float mx = fmaxf(s0[0], s1[0]);
#pragma unroll
    for (int r = 1; r < 16; ++r) mx = fmaxf(mx, fmaxf(s0[r], s1[r]));
    mx = fmaxf(mx, pair32(mx, hi));

    // defer-max: rescale O only when max grew past THR (wave-uniform branch)
    if (!__all(mx - m_r <= 8.0f)) {
      float mnew = fmaxf(m_r, mx);
      float al = exp2f((m_r - mnew) * C);
      m_r = mnew;
      li *= al;
      if (hi == 0) redL[w][l31] = al;    // alpha[q] at q=l31
      f32x4 a0 = *(const f32x4*)&redL[w][hi * 4];       // crow rows 8g+4hi+e
      f32x4 a1 = *(const f32x4*)&redL[w][8 + hi * 4];
      f32x4 a2 = *(const f32x4*)&redL[w][16 + hi * 4];
      f32x4 a3 = *(const f32x4*)&redL[w][24 + hi * 4];
#pragma unroll
      for (int e = 0; e < 4; ++e) {
        o0[e]      *= a0[e];  o1[e]      *= a0[e];
        o0[4 + e]  *= a1[e];  o1[4 + e]  *= a1[e];
        o0[8 + e]  *= a2[e];  o1[8 + e]  *= a2[e];
        o0[12 + e] *= a3[e];  o1[12 + e] *= a3[e];
      }
    }

    const float mC = m_r * C;
    float pv0[16], pv1[16];
    float sum = 0.f;
#pragma unroll
    for (int r = 0; r < 16; ++r) {
      pv0[r] = exp2f(s0[r] * C - mC);
      pv1[r] = exp2f(s1[r] * C - mC);
      sum += pv0[r] + pv1[r];
    }
    sum += pair32(sum, hi);
    li += sum;

    // P -> A-frags (k slices of 16): regs 0..7 = k 0..15, regs 8..15 = k 16..31
    s16x8 pa0 = mk_pa(pv0[0], pv0[1], pv0[2],  pv0[3],  pv0[4],  pv0[5],  pv0[6],  pv0[7]);
    s16x8 pa1 = mk_pa(pv0[8], pv0[9], pv0[10], pv0[11], pv0[12], pv0[13], pv0[14], pv0[15]);
    s16x8 pa2 = mk_pa(pv1[0], pv1[1], pv1[2],  pv1[3],  pv1[4],  pv1[5],  pv1[6],  pv1[7]);
    s16x8 pa3 = mk_pa(pv1[8], pv1[9], pv1[10], pv1[11], pv1[12], pv1[13], pv1[14], pv1[15]);

    o0 = MFMA32(pa0, vfA[0], o0);  o1 = MFMA32(pa0, vfB[0], o1);
    o0 = MFMA32(pa1, vfA[1], o0);  o1 = MFMA32(pa1, vfB[1], o1);
    o0 = MFMA32(pa2, vfA[2], o0);  o1 = MFMA32(pa2, vfB[2], o1);
    o0 = MFMA32(pa3, vfA[3], o0);  o1 = MFMA32(pa3, vfB[3], o1);
  }

  // epilogue: broadcast 1/li per q, scale, store bf16
  if (hi == 0) redL[w][l31] = 1.0f / li;
  f32x4 i0 = *(const f32x4*)&redL[w][hi * 4];
  f32x4 i1 = *(const f32x4*)&redL[w][8 + hi * 4];
  f32x4 i2 = *(const f32x4*)&redL[w][16 + hi * 4];
  f32x4 i3 = *(const f32x4*)&redL[w][24 + hi * 4];

  const int p_glob = (p >> lgHG) * 16 + h0 + (p & ((1 << lgHG) - 1));
  u16* Ab = AO + (size_t)p_glob * 131072 + (size_t)q0 * 64;
#pragma unroll
  for (int g = 0; g < 4; ++g) {
    const f32x4 iv = (g == 0) ? i0 : (g == 1) ? i1 : (g == 2) ? i2 : i3;
#pragma unroll
    for (int e = 0; e < 4; ++e) {
      int row = g * 8 + hi * 4 + e;      // crow(r,hi), r = g*4+e
      Ab[(size_t)row * 64 + l31]      = f2b(o0[g * 4 + e] * iv[e]);
      Ab[(size_t)row * 64 + 32 + l31] = f2b(o1[g * 4 + e] * iv[e]);
    }
  }
}

// ---------------------------------------------------------------------------
// Kernel 3: Out(fp32) = AO @ proj_w^T + proj_b. AO bf16 at [b*16+h][t][64],
// PW bf16 from ws. grid (8, 64), 256 thr. fp32 stores staged wide via LDS.
// ---------------------------------------------------------------------------
__global__ __launch_bounds__(256) void k_proj(
    const u16* __restrict__ AO, const u16* __restrict__ W,
    const float* __restrict__ Bias, float* __restrict__ Out)
{
  __shared__ __align__(16) u16 As[128 * 32];
  __shared__ __align__(16) u16 Bs[128 * 32];
  __shared__ __align__(16) float OStage[4 * 32 * 64];   // 32 KB
  const int tid = threadIdx.x;
  const int w = tid >> 6, lane = tid & 63, quad = lane >> 4, l16 = lane & 15;
  const int wr = w >> 1, wc = w & 1;
  const int m0 = blockIdx.y * 128, n0 = blockIdx.x * 128;

  const f32x4 z4 = {0.f, 0.f, 0.f, 0.f};
  f32x4 acc[4][4];
#pragma unroll
  for (int i = 0; i < 4; ++i)
#pragma unroll
    for (int j = 0; j < 4; ++j) acc[i][j] = z4;

  const int srow = tid >> 2;
  const int scol = (tid & 3) * 8;
  const int tok = m0 + srow;                  // tile never crosses batch bdry
  const int bb = tok >> 11, tt = tok & 2047;
  const u16* Abase = AO + (size_t)bb * 2097152 + (size_t)tt * 64;
  const u16* Bg = W + (size_t)(n0 + srow) * 1024 + scol;

  for (int k0 = 0; k0 < 1024; k0 += 32) {
    const int c0 = k0 + scol;                 // head*64 + off (within one head)
    const size_t aoff = (size_t)(c0 >> 6) * 131072 + (size_t)(c0 & 63);
    s16x8 a0 = *(const s16x8*)(Abase + aoff);
    s16x8 a1 = *(const s16x8*)(Abase + 4096 + aoff);   // tok+64 -> tt+64
    s16x8 b0 = *(const s16x8*)(Bg + k0);
    s16x8 b1 = *(const s16x8*)(Bg + (size_t)64 * 1024 + k0);
    __syncthreads();
    *(s16x8*)&As[srow * 32 + scol]        = a0;
    *(s16x8*)&As[(srow + 64) * 32 + scol] = a1;
    *(s16x8*)&Bs[srow * 32 + scol]        = b0;
    *(s16x8*)&Bs[(srow + 64) * 32 + scol] = b1;
    __syncthreads();
    s16x8 af[4], bf[4];
#pragma unroll
    for (int i = 0; i < 4; ++i)
      af[i] = *(const s16x8*)&As[(wr * 64 + i * 16 + l16) * 32 + quad * 8];
#pragma unroll
    for (int j = 0; j < 4; ++j)
      bf[j] = *(const s16x8*)&Bs[(wc * 64 + j * 16 + l16) * 32 + quad * 8];
#pragma unroll
    for (int i = 0; i < 4; ++i)
#pragma unroll
      for (int j = 0; j < 4; ++j)
        acc[i][j] = MFMA16(af[i], bf[j], acc[i][j]);
  }

  const int ncol = n0 + wc * 64;
  float bias[4];
#pragma unroll
  for (int j = 0; j < 4; ++j) bias[j] = Bias[ncol + j * 16 + l16];

  float* OS = OStage + w * 2048;        // 32 rows x 64 cols fp32
#pragma unroll
  for (int h = 0; h < 2; ++h) {
#pragma unroll
    for (int ii = 0; ii < 2; ++ii) {
      int i = h * 2 + ii;
#pragma unroll
      for (int j = 0; j < 4; ++j)
#pragma unroll
        for (int r = 0; r < 4; ++r) {
          int tl = ii * 16 + quad * 4 + r;
          OS[tl * 64 + j * 16 + l16] = acc[i][j][r] + bias[j];
        }
    }
    // same-wave ordering; wide stores: 16B/lane, 256B per 16 lanes
#pragma unroll
    for (int itr = 0; itr < 8; ++itr) {
      int task = itr * 64 + lane;
      int tl = task >> 4, g = task & 15;
      int row = m0 + wr * 64 + h * 32 + tl;
      *(f32x4*)&Out[(size_t)row * 1024 + ncol + g * 4] =
          *(const f32x4*)&OS[tl * 64 + g * 4];
    }
  }
}

// ---------------------------------------------------------------------------
extern "C" void kernel_launch(void* const* d_in, const int* in_sizes, int n_in,
                              void* d_out, int out_size, void* d_ws, size_t ws_size,
                              hipStream_t stream) {
  const float* X    = (const float*)d_in[0];   // [4,2048,1024] fp32
  const float* QKVW = (const float*)d_in[1];   // [3072,1024]
  const float* QKVB = (const float*)d_in[2];   // [3072]
  const float* PW   = (const float*)d_in[3];   // [1024,1024]
  const float* PB   = (const float*)d_in[4];   // [1024]
  float* Out = (float*)d_out;                  // [4,2048,1024] fp32
  u16* ws = (u16*)d_ws;

  // ws (bytes): HG16: 2*(PWOFF+3*segE)=52.4MB (AO aliases Qc);
  // HG<16: + dedicated AO (16.8MB).
  int HG, lgHG, ok = 1;
  if      (ws_size >= 52428800ull) { HG = 16; lgHG = 4; }
  else if (ws_size >= 44040192ull) { HG = 8;  lgHG = 3; }
  else if (ws_size >= 31457280ull) { HG = 4;  lgHG = 2; }
  else if (ws_size >= 25165824ull) { HG = 2;  lgHG = 1; }
  else                             { HG = 2;  lgHG = 1; ok = 0; }

  if (!ok) {
    k_beacon<<<dim3(4096), 256, 0, stream>>>(Out, (unsigned long long)ws_size);
    return;
  }

  const size_t segE = 524288ull << lgHG;
  u16* Qc = ws + PWOFF;
  u16* AO = (HG == 16) ? Qc : (Qc + 3 * segE);
  const int lgHB = lgHG + 6;

  k_convert_pw<<<dim3(512), 256, 0, stream>>>(PW, ws);

  const int chunks = 16 / HG;
  for (int c = 0; c < chunks; ++c) {
    int h0 = c * HG;
    k_qkv_rope<<<dim3((3 * HG) / 2, 64), 256, 0, stream>>>(
        X, QKVW, QKVB, ws, h0, lgHB, lgHG);
    k_attn<<<dim3(16, 4 * HG), 256, 0, stream>>>(ws, AO, h0, lgHG);
  }
  k_proj<<<dim3(8, 64), 256, 0, stream>>>(AO, ws, PB, Out);
}

// Round 3
// 368.193 us; speedup vs baseline: 1.4352x; 1.0879x over previous
//
#include <hip/hip_runtime.h>

typedef unsigned short u16;
typedef unsigned int   u32;
typedef __attribute__((ext_vector_type(8))) short s16x8;   // 8 x bf16 payload (4 VGPRs)
typedef __attribute__((ext_vector_type(4))) float f32x4;   // MFMA accumulator / f32 quad
typedef __attribute__((ext_vector_type(16))) float f32x16; // 32x32 MFMA accumulator

#define MFMA16(a, b, c) __builtin_amdgcn_mfma_f32_16x16x32_bf16((a), (b), (c), 0, 0, 0)
#define MFMA32(a, b, c) __builtin_amdgcn_mfma_f32_32x32x16_bf16((a), (b), (c), 0, 0, 0)
#define EXP2R(x) __builtin_amdgcn_exp2f(x)   // raw v_exp_f32 (no libm fixup)

// ws layout (bf16 elements): [PW_bf16: 1,048,576][Qc|Kc|Vc: 3*segE][AO if HG<16]
// FRAGMENT-MAJOR layouts (so k_attn hot-loop loads are contiguous 1KB/wave):
//  Qc: [p][qt32 (64)][ks (4)][lane (64)][8]   qt32 = 32-token q tile
//  Kc: [p][kt (32)][ks*2+kb (8)][lane (64)][8]
//  Vc: [p][kt (32)][ks*2+db (8)][lane (64)][8]
// frag element semantics documented at the producer epilogue below.
#define PWOFF 1048576ull

__device__ __forceinline__ u16 f2b(float f) {
  union { float f; unsigned i; } x; x.f = f;
  unsigned r = x.i + 0x7FFFu + ((x.i >> 16) & 1u);
  return (u16)(r >> 16);
}
__device__ __forceinline__ s16x8 cvt8(const float* __restrict__ p) {
  f32x4 a = *(const f32x4*)p;
  f32x4 b = *(const f32x4*)(p + 4);
  s16x8 o;
#pragma unroll
  for (int j = 0; j < 4; ++j) { o[j] = (short)f2b(a[j]); o[4 + j] = (short)f2b(b[j]); }
  return o;
}

__device__ __forceinline__ u32 cvtpk_bf16(float a, float b) {
  u32 r;
  asm("v_cvt_pk_bf16_f32 %0, %1, %2" : "=v"(r) : "v"(a), "v"(b));
  return r;
}
__device__ __forceinline__ void plswap(u32& a, u32& b) {
#if __has_builtin(__builtin_amdgcn_permlane32_swap)
  auto r = __builtin_amdgcn_permlane32_swap(a, b, false, false);
  a = r[0]; b = r[1];
#else
  asm volatile("v_permlane32_swap_b32 %0, %1" : "+v"(a), "+v"(b));
#endif
}
// Cross-half (lane <-> lane^32) partner fetch, VALU-only (no DS op in the
// softmax critical path). After plswap: a' = [a.lo|b.lo], b' = [a.hi|b.hi];
// partner of lane l is in b' for l<32 and in a' for l>=32.
__device__ __forceinline__ float pair32(float x, int hi) {
  union { float f; u32 u; } a, b;
  a.f = x; b.f = x;
  plswap(a.u, b.u);
  return hi ? a.f : b.f;
}
// Build PV A-fragment (contraction slice of 16 k) from 8 packed f32 P values.
// Lane holds P[k = crow(r,hi)] with crow = (r&3)+8*(r>>2)+4*hi; the swap gives
// lanes l<->l+32 each other's missing half: frag words (k0k1)(k2k3)(k4k5)(k6k7).
__device__ __forceinline__ s16x8 mk_pa(float e0, float e1, float e2, float e3,
                                       float e4, float e5, float e6, float e7) {
  u32 a0 = cvtpk_bf16(e0, e1), b0 = cvtpk_bf16(e4, e5);
  u32 a1 = cvtpk_bf16(e2, e3), b1 = cvtpk_bf16(e6, e7);
  plswap(a0, b0);
  plswap(a1, b1);
  union { u32 u[4]; s16x8 v; } x;
  x.u[0] = a0; x.u[1] = a1; x.u[2] = b0; x.u[3] = b1;
  return x.v;
}

// exp2 + pack + partial-sum for one group of 8 score elements (streamed so
// only ~8 pv floats are live at a time instead of 32 -> frees VGPRs for
// keeping all 16 K/V loads in flight).
#define SM_GRP(sv, ofs, pa_out, ps_out) {                                  \
    float e0 = EXP2R((sv)[(ofs) + 0] * C - mC);                            \
    float e1 = EXP2R((sv)[(ofs) + 1] * C - mC);                            \
    float e2 = EXP2R((sv)[(ofs) + 2] * C - mC);                            \
    float e3 = EXP2R((sv)[(ofs) + 3] * C - mC);                            \
    float e4 = EXP2R((sv)[(ofs) + 4] * C - mC);                            \
    float e5 = EXP2R((sv)[(ofs) + 5] * C - mC);                            \
    float e6 = EXP2R((sv)[(ofs) + 6] * C - mC);                            \
    float e7 = EXP2R((sv)[(ofs) + 7] * C - mC);                            \
    (pa_out) = mk_pa(e0, e1, e2, e3, e4, e5, e6, e7);                      \
    (ps_out) = ((e0 + e1) + (e2 + e3)) + ((e4 + e5) + (e6 + e7));          \
  }

// ---------------------------------------------------------------------------
// Beacon (only if ws too small for any path): fill d_out with 3000+wsMB.
// ---------------------------------------------------------------------------
__global__ void k_beacon(float* __restrict__ Out, unsigned long long ws_size) {
  float V = 3000.0f + fminf((float)(ws_size >> 20), 999.0f);
  size_t i = ((size_t)blockIdx.x * 256 + threadIdx.x) * 8;
#pragma unroll
  for (int j = 0; j < 8; ++j) Out[i + j] = V;
}

// ---------------------------------------------------------------------------
// proj_w fp32 [1024,1024] -> bf16 at ws[0..1048576)
// ---------------------------------------------------------------------------
__global__ void k_convert_pw(const float* __restrict__ PW, u16* __restrict__ ws) {
  size_t i = ((size_t)blockIdx.x * 256 + threadIdx.x) * 8;
  *(s16x8*)(ws + i) = cvt8(PW + i);
}

// ---------------------------------------------------------------------------
// Kernel 1: chunked QKV GEMM + bias + RoPE. fp32 in, bf16 MFMA, wide stores.
// grid ((3*HG)/2, 64), 256 thr. Writes Qc/Kc/Vc in FRAGMENT-MAJOR layout:
// each wave owns a full 64-token x 64-d tile of one head (tokens 64-aligned,
// never crossing a batch boundary), stages it in LDS (rope'd rows for Q/K,
// transposed for V), then stores the exact k_attn MFMA fragments as
// contiguous 1KB wave writes.
// ---------------------------------------------------------------------------
__global__ __launch_bounds__(256) void k_qkv_rope(
    const float* __restrict__ X, const float* __restrict__ W,
    const float* __restrict__ Bias, u16* __restrict__ ws,
    int h0, int lgHB, int lgHG)
{
  __shared__ __align__(16) u16 smem[18432];   // As[4096] Bs[4096] | epilogue 4x(64x72)
  u16* As = smem;
  u16* Bs = smem + 4096;

  const size_t segE = 524288ull << lgHG;
  u16* Qc = ws + PWOFF;
  u16* Kc = Qc + segE;
  u16* Vc = Kc + segE;

  const int tid = threadIdx.x;
  const int w = tid >> 6, lane = tid & 63, quad = lane >> 4, l16 = lane & 15;
  const int l31 = lane & 31, hi = lane >> 5;
  const int wr = w >> 1, wc = w & 1;
  const int m0 = blockIdx.y * 128, n0 = blockIdx.x * 128;
  const int HB = 1 << lgHB;

  const f32x4 z4 = {0.f, 0.f, 0.f, 0.f};
  f32x4 acc[4][4];
#pragma unroll
  for (int i = 0; i < 4; ++i)
#pragma unroll
    for (int j = 0; j < 4; ++j) acc[i][j] = z4;

  const int srow = tid >> 2;
  const int scol = (tid & 3) * 8;
  const int nlogA = n0 + srow, nlogB = nlogA + 64;
  const int wrowA = (nlogA >> lgHB) * 1024 + (h0 + ((nlogA & (HB - 1)) >> 6)) * 64 + (nlogA & 63);
  const int wrowB = (nlogB >> lgHB) * 1024 + (h0 + ((nlogB & (HB - 1)) >> 6)) * 64 + (nlogB & 63);
  const float* Ag  = X + (size_t)(m0 + srow) * 1024 + scol;
  const float* BgA = W + (size_t)wrowA * 1024 + scol;
  const float* BgB = W + (size_t)wrowB * 1024 + scol;

  for (int k0 = 0; k0 < 1024; k0 += 32) {
    s16x8 a0 = cvt8(Ag + k0);
    s16x8 a1 = cvt8(Ag + (size_t)64 * 1024 + k0);
    s16x8 b0 = cvt8(BgA + k0);
    s16x8 b1 = cvt8(BgB + k0);
    __syncthreads();
    *(s16x8*)&As[srow * 32 + scol]        = a0;
    *(s16x8*)&As[(srow + 64) * 32 + scol] = a1;
    *(s16x8*)&Bs[srow * 32 + scol]        = b0;
    *(s16x8*)&Bs[(srow + 64) * 32 + scol] = b1;
    __syncthreads();
    s16x8 af[4], bf[4];
#pragma unroll
    for (int i = 0; i < 4; ++i)
      af[i] = *(const s16x8*)&As[(wr * 64 + i * 16 + l16) * 32 + quad * 8];
#pragma unroll
    for (int j = 0; j < 4; ++j)
      bf[j] = *(const s16x8*)&Bs[(wc * 64 + j * 16 + l16) * 32 + quad * 8];
#pragma unroll
    for (int i = 0; i < 4; ++i)
#pragma unroll
      for (int j = 0; j < 4; ++j)
        acc[i][j] = MFMA16(af[i], bf[j], acc[i][j]);
  }

  const int ncol = n0 + wc * 64;              // 64-aligned -> single (which,hh)
  const int which = ncol >> lgHB;             // 0=q 1=k 2=v
  const int hh = (ncol & (HB - 1)) >> 6;
  const int cb = which * 1024 + (h0 + hh) * 64;
  const int mbase = m0 + wr * 64;
  float bias[4];
#pragma unroll
  for (int j = 0; j < 4; ++j) bias[j] = Bias[cb + j * 16 + l16];

  __syncthreads();                       // all waves done with As/Bs
  u16* OSt = smem + w * 4608;            // 64 rows x 72 (stride 144B, 16B-aligned)

  if (which == 2) {
    // V: stage TRANSPOSED tile OSt[d][tok_local] (64x72)
#pragma unroll
    for (int i = 0; i < 4; ++i)
#pragma unroll
      for (int r = 0; r < 4; ++r) {
        int tl = i * 16 + quad * 4 + r;
#pragma unroll
        for (int j = 0; j < 4; ++j)
          OSt[(j * 16 + l16) * 72 + tl] = f2b(acc[i][j][r] + bias[j]);
      }
  } else {
    const float LC = 0.1716750968f;      // log2(40)/31
    float fr0 = exp2f((float)l16 * LC);            // freq for dim l16
    float fr1 = exp2f((float)(16 + l16) * LC);     // freq for dim 16+l16
#pragma unroll
    for (int i = 0; i < 4; ++i)
#pragma unroll
      for (int r = 0; r < 4; ++r) {
        int tl = i * 16 + quad * 4 + r;
        int tok = mbase + tl;
        // revolutions = (t/2048)*freq; v_sin/v_cos take revolutions
        float ps = (float)(tok & 2047) * (1.0f / 2048.0f);
        float rv0 = ps * fr0; rv0 -= floorf(rv0);
        float rv1 = ps * fr1; rv1 -= floorf(rv1);
        float s0 = __builtin_amdgcn_sinf(rv0), c0 = __builtin_amdgcn_cosf(rv0);
        float s1 = __builtin_amdgcn_sinf(rv1), c1 = __builtin_amdgcn_cosf(rv1);
        float x10 = acc[i][0][r] + bias[0], x11 = acc[i][1][r] + bias[1];
        float x20 = acc[i][2][r] + bias[2], x21 = acc[i][3][r] + bias[3];
        OSt[tl * 72 + l16]      = f2b(x10 * c0 - x20 * s0);
        OSt[tl * 72 + 16 + l16] = f2b(x11 * c1 - x21 * s1);
        OSt[tl * 72 + 32 + l16] = f2b(x10 * s0 + x20 * c0);
        OSt[tl * 72 + 48 + l16] = f2b(x11 * s1 + x21 * c1);
      }
  }
  // fragment-major stores: same-wave LDS ordering; 16B/lane, 1KB/wave-instr
  const int bb = mbase >> 11, tt0 = mbase & 2047;
  const int pp = (bb << lgHG) + hh;
  if (which == 2) {
    // Vc frag (kt, fi=ks*2+db): lane holds V^T[d=db*32+l31][kt*64+ks*16+hi*8+j]
    u16* D = Vc + ((size_t)pp * 32 + (tt0 >> 6)) * 4096;
#pragma unroll
    for (int fi = 0; fi < 8; ++fi) {
      int ks = fi >> 1, db = fi & 1;
      *(s16x8*)&D[fi * 512 + lane * 8] =
          *(const s16x8*)&OSt[(db * 32 + l31) * 72 + ks * 16 + hi * 8];
    }
  } else if (which == 1) {
    // Kc frag (kt, fi=ks*2+kb): lane holds K[kt*64+kb*32+l31][ks*16+hi*8+j]
    u16* D = Kc + ((size_t)pp * 32 + (tt0 >> 6)) * 4096;
#pragma unroll
    for (int fi = 0; fi < 8; ++fi) {
      int ks = fi >> 1, kb = fi & 1;
      *(s16x8*)&D[fi * 512 + lane * 8] =
          *(const s16x8*)&OSt[(kb * 32 + l31) * 72 + ks * 16 + hi * 8];
    }
  } else {
    // Qc frag (qt32, ks): lane holds Q[qt32*32+l31][ks*16+hi*8+j]
    u16* D = Qc + ((size_t)pp * 64 + (tt0 >> 5)) * 2048;
#pragma unroll
    for (int fi = 0; fi < 8; ++fi) {
      int qh = fi >> 2, ks = fi & 3;
      *(s16x8*)&D[(size_t)qh * 2048 + ks * 512 + lane * 8] =
          *(const s16x8*)&OSt[(qh * 32 + l31) * 72 + ks * 16 + hi * 8];
    }
  }
}

// ---------------------------------------------------------------------------
// Kernel 2: flash attention, swapped-operand 32x32 MFMA, zero LDS in hot loop,
// ALL hot-loop global loads fragment-major (contiguous 1KB per wave instr).
// grid (16, 4*HG), 256 thr (4 indep waves, 32 q-rows each).
//  - QK^T computed as mfma32(K_frag, Q_frag): lane owns P[k=crow(r,hi)][q=l&31]
//  - softmax stats in-register; cross-half reduce via permlane32 (VALU-only)
//  - raw v_exp_f32 (EXP2R), tree-shaped max/sum reductions (short dep chains)
//  - streamed exp->cvt_pk->psum in groups of 8 (low register pressure so all
//    16 K/V loads stay in flight across the softmax)
//  - launch_bounds(256,4): 128-VGPR cap == exactly 4 waves/SIMD (free headroom)
//  - defer-max (THR=8 raw): O-rescale only when running max grows
//  - bijective XCD swizzle: each XCD owns P/8 heads -> 4MB KV set in its L2
// AO written bf16 [b*16+head][t][64] (aliases Qc when HG=16: each wave reads
// its own Q-frag window first, then writes only that window).
// ---------------------------------------------------------------------------
__global__ __launch_bounds__(256, 4) void k_attn(
    u16* __restrict__ ws, u16* __restrict__ AO, int h0, int lgHG)
{
  __shared__ float redL[4][32];          // per-wave alpha / inv-li broadcast

  const size_t segE = 524288ull << lgHG;
  const u16* Qg = ws + PWOFF;
  const u16* Kg = Qg + segE;
  const u16* Vg = Kg + segE;

  const int tid = threadIdx.x;
  const int w = tid >> 6, lane = tid & 63;
  const int l31 = lane & 31, hi = lane >> 5;

  // XCD swizzle: n = by*16 + bx; xcd = n&7 gets heads [xcd*P/8, ...)
  const int P = 4 << lgHG;
  const int n = blockIdx.y * 16 + blockIdx.x;
  const int mm = n >> 3;
  const int p  = (n & 7) * (P >> 3) + (mm >> 4);
  const int qt = mm & 15;

  const u16* Kb = Kg + (size_t)p * 131072;
  const u16* Vb = Vg + (size_t)p * 131072;
  const int q0 = qt * 128 + w * 32;

  // Q fragments: frag-major, contiguous per wave
  const u16* Qt = Qg + (size_t)p * 131072 + (size_t)(qt * 4 + w) * 2048;
  s16x8 qf[4];
#pragma unroll
  for (int ks = 0; ks < 4; ++ks)
    qf[ks] = *(const s16x8*)&Qt[ks * 512 + lane * 8];

  f32x16 o0, o1;                         // O[q=crow(r,hi)][d=l31 (+32)]
#pragma unroll
  for (int r = 0; r < 16; ++r) { o0[r] = 0.f; o1[r] = 0.f; }
  float m_r = -1e30f, li = 0.f;
  const float C = 0.1803368801f;         // 0.125 * log2(e)

  for (int kt = 0; kt < 32; ++kt) {
    const u16* Kt = Kb + (size_t)kt * 4096;
    const u16* Vt = Vb + (size_t)kt * 4096;
    s16x8 kfA[4], kfB[4], vfA[4], vfB[4];
#pragma unroll
    for (int ks = 0; ks < 4; ++ks) {
      kfA[ks] = *(const s16x8*)&Kt[(ks * 2 + 0) * 512 + lane * 8];
      kfB[ks] = *(const s16x8*)&Kt[(ks * 2 + 1) * 512 + lane * 8];
    }
#pragma unroll
    for (int ks = 0; ks < 4; ++ks) {
      vfA[ks] = *(const s16x8*)&Vt[(ks * 2 + 0) * 512 + lane * 8];
      vfB[ks] = *(const s16x8*)&Vt[(ks * 2 + 1) * 512 + lane * 8];
    }

    // swapped QK^T: C[row = k-local = crow(r,hi)][col = q = l31]
    f32x16 s0, s1;
#pragma unroll
    for (int r = 0; r < 16; ++r) { s0[r] = 0.f; s1[r] = 0.f; }
#pragma unroll
    for (int ks = 0; ks < 4; ++ks) {
      s0 = MFMA32(kfA[ks], qf[ks], s0);
      s1 = MFMA32(kfB[ks], qf[ks], s1);
    }

    // tree max over the 32 locally-held scores (depth ~5, v_max3-friendly)
    float m8[8];
#pragma unroll
    for (int r = 0; r < 8; ++r)
      m8[r] = fmaxf(fmaxf(s0[r], s0[r + 8]), fmaxf(s1[r], s1[r + 8]));
    float mx = fmaxf(fmaxf(fmaxf(m8[0], m8[1]), fmaxf(m8[2], m8[3])),
                     fmaxf(fmaxf(m8[4], m8[5]), fmaxf(m8[6], m8[7])));
    mx = fmaxf(mx, pair32(mx, hi));

    // defer-max: rescale O only when max grew past THR (wave-uniform branch)
    if (!__all(mx - m_r <= 8.0f)) {
      float mnew = fmaxf(m_r, mx);
      float al = EXP2R((m_r - mnew) * C);
      m_r = mnew;
      li *= al;
      if (hi == 0) redL[w][l31] = al;    // alpha[q] at q=l31
      f32x4 a0 = *(const f32x4*)&redL[w][hi * 4];       // crow rows 8g+4hi+e
      f32x4 a1 = *(const f32x4*)&redL[w][8 + hi * 4];
      f32x4 a2 = *(const f32x4*)&redL[w][16 + hi * 4];
      f32x4 a3 = *(const f32x4*)&redL[w][24 + hi * 4];
#pragma unroll
      for (int e = 0; e < 4; ++e) {
        o0[e]      *= a0[e];  o1[e]      *= a0[e];
        o0[4 + e]  *= a1[e];  o1[4 + e]  *= a1[e];
        o0[8 + e]  *= a2[e];  o1[8 + e]  *= a2[e];
        o0[12 + e] *= a3[e];  o1[12 + e] *= a3[e];
      }
    }

    const float mC = m_r * C;
    s16x8 pa0, pa1, pa2, pa3;
    float ps0, ps1, ps2, ps3;
    SM_GRP(s0, 0, pa0, ps0);
    SM_GRP(s0, 8, pa1, ps1);
    SM_GRP(s1, 0, pa2, ps2);
    SM_GRP(s1, 8, pa3, ps3);
    float sum = (ps0 + ps1) + (ps2 + ps3);
    sum += pair32(sum, hi);
    li += sum;

    o0 = MFMA32(pa0, vfA[0], o0);  o1 = MFMA32(pa0, vfB[0], o1);
    o0 = MFMA32(pa1, vfA[1], o0);  o1 = MFMA32(pa1, vfB[1], o1);
    o0 = MFMA32(pa2, vfA[2], o0);  o1 = MFMA32(pa2, vfB[2], o1);
    o0 = MFMA32(pa3, vfA[3], o0);  o1 = MFMA32(pa3, vfB[3], o1);
  }

  // epilogue: broadcast 1/li per q, scale, store bf16
  if (hi == 0) redL[w][l31] = 1.0f / li;
  f32x4 i0 = *(const f32x4*)&redL[w][hi * 4];
  f32x4 i1 = *(const f32x4*)&redL[w][8 + hi * 4];
  f32x4 i2 = *(const f32x4*)&redL[w][16 + hi * 4];
  f32x4 i3 = *(const f32x4*)&redL[w][24 + hi * 4];

  const int p_glob = (p >> lgHG) * 16 + h0 + (p & ((1 << lgHG) - 1));
  u16* Ab = AO + (size_t)p_glob * 131072 + (size_t)q0 * 64;
#pragma unroll
  for (int g = 0; g < 4; ++g) {
    const f32x4 iv = (g == 0) ? i0 : (g == 1) ? i1 : (g == 2) ? i2 : i3;
#pragma unroll
    for (int e = 0; e < 4; ++e) {
      int row = g * 8 + hi * 4 + e;      // crow(r,hi), r = g*4+e
      Ab[(size_t)row * 64 + l31]      = f2b(o0[g * 4 + e] * iv[e]);
      Ab[(size_t)row * 64 + 32 + l31] = f2b(o1[g * 4 + e] * iv[e]);
    }
  }
}

// ---------------------------------------------------------------------------
// Kernel 3: Out(fp32) = AO @ proj_w^T + proj_b. AO bf16 at [b*16+h][t][64],
// PW bf16 from ws. grid (8, 64), 256 thr. fp32 stores staged wide via LDS.
// ---------------------------------------------------------------------------
__global__ __launch_bounds__(256) void k_proj(
    const u16* __restrict__ AO, const u16* __restrict__ W,
    const float* __restrict__ Bias, float* __restrict__ Out)
{
  __shared__ __align__(16) u16 As[128 * 32];
  __shared__ __align__(16) u16 Bs[128 * 32];
  __shared__ __align__(16) float OStage[4 * 32 * 64];   // 32 KB
  const int tid = threadIdx.x;
  const int w = tid >> 6, lane = tid & 63, quad = lane >> 4, l16 = lane & 15;
  const int wr = w >> 1, wc = w & 1;
  const int m0 = blockIdx.y * 128, n0 = blockIdx.x * 128;

  const f32x4 z4 = {0.f, 0.f, 0.f, 0.f};
  f32x4 acc[4][4];
#pragma unroll
  for (int i = 0; i < 4; ++i)
#pragma unroll
    for (int j = 0; j < 4; ++j) acc[i][j] = z4;

  const int srow = tid >> 2;
  const int scol = (tid & 3) * 8;
  const int tok = m0 + srow;                  // tile never crosses batch bdry
  const int bb = tok >> 11, tt = tok & 2047;
  const u16* Abase = AO + (size_t)bb * 2097152 + (size_t)tt * 64;
  const u16* Bg = W + (size_t)(n0 + srow) * 1024 + scol;

  for (int k0 = 0; k0 < 1024; k0 += 32) {
    const int c0 = k0 + scol;                 // head*64 + off (within one head)
    const size_t aoff = (size_t)(c0 >> 6) * 131072 + (size_t)(c0 & 63);
    s16x8 a0 = *(const s16x8*)(Abase + aoff);
    s16x8 a1 = *(const s16x8*)(Abase + 4096 + aoff);   // tok+64 -> tt+64
    s16x8 b0 = *(const s16x8*)(Bg + k0);
    s16x8 b1 = *(const s16x8*)(Bg + (size_t)64 * 1024 + k0);
    __syncthreads();
    *(s16x8*)&As[srow * 32 + scol]        = a0;
    *(s16x8*)&As[(srow + 64) * 32 + scol] = a1;
    *(s16x8*)&Bs[srow * 32 + scol]        = b0;
    *(s16x8*)&Bs[(srow + 64) * 32 + scol] = b1;
    __syncthreads();
    s16x8 af[4], bf[4];
#pragma unroll
    for (int i = 0; i < 4; ++i)
      af[i] = *(const s16x8*)&As[(wr * 64 + i * 16 + l16) * 32 + quad * 8];
#pragma unroll
    for (int j = 0; j < 4; ++j)
      bf[j] = *(const s16x8*)&Bs[(wc * 64 + j * 16 + l16) * 32 + quad * 8];
#pragma unroll
    for (int i = 0; i < 4; ++i)
#pragma unroll
      for (int j = 0; j < 4; ++j)
        acc[i][j] = MFMA16(af[i], bf[j], acc[i][j]);
  }

  const int ncol = n0 + wc * 64;
  float bias[4];
#pragma unroll
  for (int j = 0; j < 4; ++j) bias[j] = Bias[ncol + j * 16 + l16];

  float* OS = OStage + w * 2048;        // 32 rows x 64 cols fp32
#pragma unroll
  for (int h = 0; h < 2; ++h) {
#pragma unroll
    for (int ii = 0; ii < 2; ++ii) {
      int i = h * 2 + ii;
#pragma unroll
      for (int j = 0; j < 4; ++j)
#pragma unroll
        for (int r = 0; r < 4; ++r) {
          int tl = ii * 16 + quad * 4 + r;
          OS[tl * 64 + j * 16 + l16] = acc[i][j][r] + bias[j];
        }
    }
    // same-wave ordering; wide stores: 16B/lane, 256B per 16 lanes
#pragma unroll
    for (int itr = 0; itr < 8; ++itr) {
      int task = itr * 64 + lane;
      int tl = task >> 4, g = task & 15;
      int row = m0 + wr * 64 + h * 32 + tl;
      *(f32x4*)&Out[(size_t)row * 1024 + ncol + g * 4] =
          *(const f32x4*)&OS[tl * 64 + g * 4];
    }
  }
}

// ---------------------------------------------------------------------------
extern "C" void kernel_launch(void* const* d_in, const int* in_sizes, int n_in,
                              void* d_out, int out_size, void* d_ws, size_t ws_size,
                              hipStream_t stream) {
  const float* X    = (const float*)d_in[0];   // [4,2048,1024] fp32
  const float* QKVW = (const float*)d_in[1];   // [3072,1024]
  const float* QKVB = (const float*)d_in[2];   // [3072]
  const float* PW   = (const float*)d_in[3];   // [1024,1024]
  const float* PB   = (const float*)d_in[4];   // [1024]
  float* Out = (float*)d_out;                  // [4,2048,1024] fp32
  u16* ws = (u16*)d_ws;

  // ws (bytes): HG16: 2*(PWOFF+3*segE)=52.4MB (AO aliases Qc);
  // HG<16: + dedicated AO (16.8MB).
  int HG, lgHG, ok = 1;
  if      (ws_size >= 52428800ull) { HG = 16; lgHG = 4; }
  else if (ws_size >= 44040192ull) { HG = 8;  lgHG = 3; }
  else if (ws_size >= 31457280ull) { HG = 4;  lgHG = 2; }
  else if (ws_size >= 25165824ull) { HG = 2;  lgHG = 1; }
  else                             { HG = 2;  lgHG = 1; ok = 0; }

  if (!ok) {
    k_beacon<<<dim3(4096), 256, 0, stream>>>(Out, (unsigned long long)ws_size);
    return;
  }

  const size_t segE = 524288ull << lgHG;
  u16* Qc = ws + PWOFF;
  u16* AO = (HG == 16) ? Qc : (Qc + 3 * segE);
  const int lgHB = lgHG + 6;

  k_convert_pw<<<dim3(512), 256, 0, stream>>>(PW, ws);

  const int chunks = 16 / HG;
  for (int c = 0; c < chunks; ++c) {
    int h0 = c * HG;
    k_qkv_rope<<<dim3((3 * HG) / 2, 64), 256, 0, stream>>>(
        X, QKVW, QKVB, ws, h0, lgHB, lgHG);
    k_attn<<<dim3(16, 4 * HG), 256, 0, stream>>>(ws, AO, h0, lgHG);
  }
  k_proj<<<dim3(8, 64), 256, 0, stream>>>(AO, ws, PB, Out);
}

// Round 4
// 343.665 us; speedup vs baseline: 1.5376x; 1.0714x over previous
//
#include <hip/hip_runtime.h>

typedef unsigned short u16;
typedef unsigned int   u32;
typedef __attribute__((ext_vector_type(8))) short s16x8;   // 8 x bf16 payload (4 VGPRs)
typedef __attribute__((ext_vector_type(4))) float f32x4;   // MFMA accumulator / f32 quad
typedef __attribute__((ext_vector_type(16))) float f32x16; // 32x32 MFMA accumulator

#define MFMA16(a, b, c) __builtin_amdgcn_mfma_f32_16x16x32_bf16((a), (b), (c), 0, 0, 0)
#define MFMA32(a, b, c) __builtin_amdgcn_mfma_f32_32x32x16_bf16((a), (b), (c), 0, 0, 0)
#define EXP2R(x) __builtin_amdgcn_exp2f(x)   // raw v_exp_f32 (no libm fixup)

// ws layout (bf16 elements): [PW_bf16: 1,048,576][Qc|Kc|Vc: 3*segE][AO if HG<16]
// FRAGMENT-MAJOR layouts (so k_attn hot-loop loads are contiguous 1KB/wave):
//  Qc: [p][qt32 (64)][ks (4)][lane (64)][8]   qt32 = 32-token q tile
//  Kc: [p][kt (32)][ks*2+kb (8)][lane (64)][8]
//  Vc: [p][kt (32)][ks*2+db (8)][lane (64)][8]
#define PWOFF 1048576ull

__device__ __forceinline__ u16 f2b(float f) {
  union { float f; unsigned i; } x; x.f = f;
  unsigned r = x.i + 0x7FFFu + ((x.i >> 16) & 1u);
  return (u16)(r >> 16);
}
__device__ __forceinline__ u32 cvtpk_bf16(float a, float b) {
  u32 r;
  asm("v_cvt_pk_bf16_f32 %0, %1, %2" : "=v"(r) : "v"(a), "v"(b));
  return r;
}
// fp32x8 -> bf16x8 via v_cvt_pk_bf16_f32 (RNE, bit-identical to f2b; 4 VALU
// ops instead of ~32 — the r3 counters showed staging cvt dominated VALU).
__device__ __forceinline__ s16x8 cvt8(const float* __restrict__ p) {
  f32x4 a = *(const f32x4*)p;
  f32x4 b = *(const f32x4*)(p + 4);
  union { u32 u[4]; s16x8 v; } o;
  o.u[0] = cvtpk_bf16(a[0], a[1]);
  o.u[1] = cvtpk_bf16(a[2], a[3]);
  o.u[2] = cvtpk_bf16(b[0], b[1]);
  o.u[3] = cvtpk_bf16(b[2], b[3]);
  return o.v;
}

__device__ __forceinline__ void plswap(u32& a, u32& b) {
#if __has_builtin(__builtin_amdgcn_permlane32_swap)
  auto r = __builtin_amdgcn_permlane32_swap(a, b, false, false);
  a = r[0]; b = r[1];
#else
  asm volatile("v_permlane32_swap_b32 %0, %1" : "+v"(a), "+v"(b));
#endif
}
// Cross-half (lane <-> lane^32) partner fetch, VALU-only.
__device__ __forceinline__ float pair32(float x, int hi) {
  union { float f; u32 u; } a, b;
  a.f = x; b.f = x;
  plswap(a.u, b.u);
  return hi ? a.f : b.f;
}
// Build PV A-fragment (contraction slice of 16 k) from 8 packed f32 P values.
// Lane holds P[k = crow(r,hi)] with crow = (r&3)+8*(r>>2)+4*hi; the swap gives
// lanes l<->l+32 each other's missing half: frag words (k0k1)(k2k3)(k4k5)(k6k7).
__device__ __forceinline__ s16x8 mk_pa(float e0, float e1, float e2, float e3,
                                       float e4, float e5, float e6, float e7) {
  u32 a0 = cvtpk_bf16(e0, e1), b0 = cvtpk_bf16(e4, e5);
  u32 a1 = cvtpk_bf16(e2, e3), b1 = cvtpk_bf16(e6, e7);
  plswap(a0, b0);
  plswap(a1, b1);
  union { u32 u[4]; s16x8 v; } x;
  x.u[0] = a0; x.u[1] = a1; x.u[2] = b0; x.u[3] = b1;
  return x.v;
}

// exp2 + pack + partial-sum for one group of 8 score elements (streamed: ~8
// live pv floats instead of 32).
#define SM_GRP(sv, ofs, pa_out, ps_out) {                                  \
    float e0 = EXP2R((sv)[(ofs) + 0] * C - mC);                            \
    float e1 = EXP2R((sv)[(ofs) + 1] * C - mC);                            \
    float e2 = EXP2R((sv)[(ofs) + 2] * C - mC);                            \
    float e3 = EXP2R((sv)[(ofs) + 3] * C - mC);                            \
    float e4 = EXP2R((sv)[(ofs) + 4] * C - mC);                            \
    float e5 = EXP2R((sv)[(ofs) + 5] * C - mC);                            \
    float e6 = EXP2R((sv)[(ofs) + 6] * C - mC);                            \
    float e7 = EXP2R((sv)[(ofs) + 7] * C - mC);                            \
    (pa_out) = mk_pa(e0, e1, e2, e3, e4, e5, e6, e7);                      \
    (ps_out) = ((e0 + e1) + (e2 + e3)) + ((e4 + e5) + (e6 + e7));          \
  }

// ---------------------------------------------------------------------------
// Beacon (only if ws too small for any path): fill d_out with 3000+wsMB.
// ---------------------------------------------------------------------------
__global__ void k_beacon(float* __restrict__ Out, unsigned long long ws_size) {
  float V = 3000.0f + fminf((float)(ws_size >> 20), 999.0f);
  size_t i = ((size_t)blockIdx.x * 256 + threadIdx.x) * 8;
#pragma unroll
  for (int j = 0; j < 8; ++j) Out[i + j] = V;
}

// ---------------------------------------------------------------------------
// proj_w fp32 [1024,1024] -> bf16 at ws[0..1048576)
// ---------------------------------------------------------------------------
__global__ void k_convert_pw(const float* __restrict__ PW, u16* __restrict__ ws) {
  size_t i = ((size_t)blockIdx.x * 256 + threadIdx.x) * 8;
  *(s16x8*)(ws + i) = cvt8(PW + i);
}

// ---------------------------------------------------------------------------
// Kernel 1: chunked QKV GEMM + bias + RoPE. fp32 in, bf16 MFMA, wide stores.
// grid ((3*HG)/2, 64), 256 thr. Fragment-major outputs (see top).
// r4: cvt_pk staging, 1-stage prefetch pipeline (loads hide under MFMA),
// XCD-grouped swizzle (8 consecutive M-panels per XCD -> X panel L2-resident).
// ---------------------------------------------------------------------------
__global__ __launch_bounds__(256, 4) void k_qkv_rope(
    const float* __restrict__ X, const float* __restrict__ W,
    const float* __restrict__ Bias, u16* __restrict__ ws,
    int h0, int lgHB, int lgHG)
{
  __shared__ __align__(16) u16 smem[18432];   // As[4096] Bs[4096] | epilogue 4x(64x72)
  u16* As = smem;
  u16* Bs = smem + 4096;

  const size_t segE = 524288ull << lgHG;
  u16* Qc = ws + PWOFF;
  u16* Kc = Qc + segE;
  u16* Vc = Kc + segE;

  const int tid = threadIdx.x;
  const int w = tid >> 6, lane = tid & 63, quad = lane >> 4, l16 = lane & 15;
  const int l31 = lane & 31, hi = lane >> 5;
  const int wr = w >> 1, wc = w & 1;
  const int HB = 1 << lgHB;

  // XCD-grouped bijective swizzle: hw linear id -> logical (by-major chunks).
  // nwg = gx*64 is a multiple of 8 for every HG.
  const int gx = gridDim.x;
  const int hw = blockIdx.y * gx + blockIdx.x;
  const int cpx = (gx << 6) >> 3;             // nwg/8
  const int lg = (hw & 7) * cpx + (hw >> 3);
  const int m0 = (lg / gx) * 128, n0 = (lg % gx) * 128;

  const f32x4 z4 = {0.f, 0.f, 0.f, 0.f};
  f32x4 acc[4][4];
#pragma unroll
  for (int i = 0; i < 4; ++i)
#pragma unroll
    for (int j = 0; j < 4; ++j) acc[i][j] = z4;

  const int srow = tid >> 2;
  const int scol = (tid & 3) * 8;
  const int nlogA = n0 + srow, nlogB = nlogA + 64;
  const int wrowA = (nlogA >> lgHB) * 1024 + (h0 + ((nlogA & (HB - 1)) >> 6)) * 64 + (nlogA & 63);
  const int wrowB = (nlogB >> lgHB) * 1024 + (h0 + ((nlogB & (HB - 1)) >> 6)) * 64 + (nlogB & 63);
  const float* Ag  = X + (size_t)(m0 + srow) * 1024 + scol;
  const float* BgA = W + (size_t)wrowA * 1024 + scol;
  const float* BgB = W + (size_t)wrowB * 1024 + scol;

  // 1-stage software pipeline: regs hold (converted) tile k+1 while MFMA runs.
  s16x8 ra0 = cvt8(Ag);
  s16x8 ra1 = cvt8(Ag + (size_t)64 * 1024);
  s16x8 rb0 = cvt8(BgA);
  s16x8 rb1 = cvt8(BgB);

  for (int k0 = 0; k0 < 1024; k0 += 32) {
    __syncthreads();
    *(s16x8*)&As[srow * 32 + scol]        = ra0;
    *(s16x8*)&As[(srow + 64) * 32 + scol] = ra1;
    *(s16x8*)&Bs[srow * 32 + scol]        = rb0;
    *(s16x8*)&Bs[(srow + 64) * 32 + scol] = rb1;
    __syncthreads();
    if (k0 < 992) {                       // issue next-tile loads before MFMA
      ra0 = cvt8(Ag + k0 + 32);
      ra1 = cvt8(Ag + (size_t)64 * 1024 + k0 + 32);
      rb0 = cvt8(BgA + k0 + 32);
      rb1 = cvt8(BgB + k0 + 32);
    }
    s16x8 af[4], bf[4];
#pragma unroll
    for (int i = 0; i < 4; ++i)
      af[i] = *(const s16x8*)&As[(wr * 64 + i * 16 + l16) * 32 + quad * 8];
#pragma unroll
    for (int j = 0; j < 4; ++j)
      bf[j] = *(const s16x8*)&Bs[(wc * 64 + j * 16 + l16) * 32 + quad * 8];
#pragma unroll
    for (int i = 0; i < 4; ++i)
#pragma unroll
      for (int j = 0; j < 4; ++j)
        acc[i][j] = MFMA16(af[i], bf[j], acc[i][j]);
  }

  const int ncol = n0 + wc * 64;              // 64-aligned -> single (which,hh)
  const int which = ncol >> lgHB;             // 0=q 1=k 2=v
  const int hh = (ncol & (HB - 1)) >> 6;
  const int cb = which * 1024 + (h0 + hh) * 64;
  const int mbase = m0 + wr * 64;
  float bias[4];
#pragma unroll
  for (int j = 0; j < 4; ++j) bias[j] = Bias[cb + j * 16 + l16];

  __syncthreads();                       // all waves done with As/Bs
  u16* OSt = smem + w * 4608;            // 64 rows x 72 (stride 144B, 16B-aligned)

  if (which == 2) {
    // V: stage TRANSPOSED tile OSt[d][tok_local] (64x72)
#pragma unroll
    for (int i = 0; i < 4; ++i)
#pragma unroll
      for (int r = 0; r < 4; ++r) {
        int tl = i * 16 + quad * 4 + r;
#pragma unroll
        for (int j = 0; j < 4; ++j)
          OSt[(j * 16 + l16) * 72 + tl] = f2b(acc[i][j][r] + bias[j]);
      }
  } else {
    const float LC = 0.1716750968f;      // log2(40)/31
    float fr0 = exp2f((float)l16 * LC);            // freq for dim l16
    float fr1 = exp2f((float)(16 + l16) * LC);     // freq for dim 16+l16
#pragma unroll
    for (int i = 0; i < 4; ++i)
#pragma unroll
      for (int r = 0; r < 4; ++r) {
        int tl = i * 16 + quad * 4 + r;
        int tok = mbase + tl;
        // revolutions = (t/2048)*freq; v_sin/v_cos take revolutions
        float ps = (float)(tok & 2047) * (1.0f / 2048.0f);
        float rv0 = ps * fr0; rv0 -= floorf(rv0);
        float rv1 = ps * fr1; rv1 -= floorf(rv1);
        float s0 = __builtin_amdgcn_sinf(rv0), c0 = __builtin_amdgcn_cosf(rv0);
        float s1 = __builtin_amdgcn_sinf(rv1), c1 = __builtin_amdgcn_cosf(rv1);
        float x10 = acc[i][0][r] + bias[0], x11 = acc[i][1][r] + bias[1];
        float x20 = acc[i][2][r] + bias[2], x21 = acc[i][3][r] + bias[3];
        OSt[tl * 72 + l16]      = f2b(x10 * c0 - x20 * s0);
        OSt[tl * 72 + 16 + l16] = f2b(x11 * c1 - x21 * s1);
        OSt[tl * 72 + 32 + l16] = f2b(x10 * s0 + x20 * c0);
        OSt[tl * 72 + 48 + l16] = f2b(x11 * s1 + x21 * c1);
      }
  }
  // fragment-major stores: same-wave LDS ordering; 16B/lane, 1KB/wave-instr
  const int bb = mbase >> 11, tt0 = mbase & 2047;
  const int pp = (bb << lgHG) + hh;
  if (which == 2) {
    // Vc frag (kt, fi=ks*2+db): lane holds V^T[d=db*32+l31][kt*64+ks*16+hi*8+j]
    u16* D = Vc + ((size_t)pp * 32 + (tt0 >> 6)) * 4096;
#pragma unroll
    for (int fi = 0; fi < 8; ++fi) {
      int ks = fi >> 1, db = fi & 1;
      *(s16x8*)&D[fi * 512 + lane * 8] =
          *(const s16x8*)&OSt[(db * 32 + l31) * 72 + ks * 16 + hi * 8];
    }
  } else if (which == 1) {
    // Kc frag (kt, fi=ks*2+kb): lane holds K[kt*64+kb*32+l31][ks*16+hi*8+j]
    u16* D = Kc + ((size_t)pp * 32 + (tt0 >> 6)) * 4096;
#pragma unroll
    for (int fi = 0; fi < 8; ++fi) {
      int ks = fi >> 1, kb = fi & 1;
      *(s16x8*)&D[fi * 512 + lane * 8] =
          *(const s16x8*)&OSt[(kb * 32 + l31) * 72 + ks * 16 + hi * 8];
    }
  } else {
    // Qc frag (qt32, ks): lane holds Q[qt32*32+l31][ks*16+hi*8+j]
    u16* D = Qc + ((size_t)pp * 64 + (tt0 >> 5)) * 2048;
#pragma unroll
    for (int fi = 0; fi < 8; ++fi) {
      int qh = fi >> 2, ks = fi & 3;
      *(s16x8*)&D[(size_t)qh * 2048 + ks * 512 + lane * 8] =
          *(const s16x8*)&OSt[(qh * 32 + l31) * 72 + ks * 16 + hi * 8];
    }
  }
}

// ---------------------------------------------------------------------------
// Kernel 2: flash attention, swapped-operand 32x32 MFMA, zero LDS in hot loop,
// all hot-loop global loads fragment-major (contiguous 1KB per wave instr).
// grid (16, 4*HG), 256 thr (4 indep waves, 32 q-rows each).
// ---------------------------------------------------------------------------
__global__ __launch_bounds__(256, 4) void k_attn(
    u16* __restrict__ ws, u16* __restrict__ AO, int h0, int lgHG)
{
  __shared__ float redL[4][32];          // per-wave alpha / inv-li broadcast

  const size_t segE = 524288ull << lgHG;
  const u16* Qg = ws + PWOFF;
  const u16* Kg = Qg + segE;
  const u16* Vg = Kg + segE;

  const int tid = threadIdx.x;
  const int w = tid >> 6, lane = tid & 63;
  const int l31 = lane & 31, hi = lane >> 5;

  // XCD swizzle: n = by*16 + bx; xcd = n&7 gets heads [xcd*P/8, ...)
  const int P = 4 << lgHG;
  const int n = blockIdx.y * 16 + blockIdx.x;
  const int mm = n >> 3;
  const int p  = (n & 7) * (P >> 3) + (mm >> 4);
  const int qt = mm & 15;

  const u16* Kb = Kg + (size_t)p * 131072;
  const u16* Vb = Vg + (size_t)p * 131072;
  const int q0 = qt * 128 + w * 32;

  // Q fragments: frag-major, contiguous per wave
  const u16* Qt = Qg + (size_t)p * 131072 + (size_t)(qt * 4 + w) * 2048;
  s16x8 qf[4];
#pragma unroll
  for (int ks = 0; ks < 4; ++ks)
    qf[ks] = *(const s16x8*)&Qt[ks * 512 + lane * 8];

  f32x16 o0, o1;                         // O[q=crow(r,hi)][d=l31 (+32)]
#pragma unroll
  for (int r = 0; r < 16; ++r) { o0[r] = 0.f; o1[r] = 0.f; }
  float m_r = -1e30f, li = 0.f;
  const float C = 0.1803368801f;         // 0.125 * log2(e)

  for (int kt = 0; kt < 32; ++kt) {
    const u16* Kt = Kb + (size_t)kt * 4096;
    const u16* Vt = Vb + (size_t)kt * 4096;
    s16x8 kfA[4], kfB[4], vfA[4], vfB[4];
#pragma unroll
    for (int ks = 0; ks < 4; ++ks) {
      kfA[ks] = *(const s16x8*)&Kt[(ks * 2 + 0) * 512 + lane * 8];
      kfB[ks] = *(const s16x8*)&Kt[(ks * 2 + 1) * 512 + lane * 8];
    }
#pragma unroll
    for (int ks = 0; ks < 4; ++ks) {
      vfA[ks] = *(const s16x8*)&Vt[(ks * 2 + 0) * 512 + lane * 8];
      vfB[ks] = *(const s16x8*)&Vt[(ks * 2 + 1) * 512 + lane * 8];
    }

    // swapped QK^T: C[row = k-local = crow(r,hi)][col = q = l31]
    f32x16 s0, s1;
#pragma unroll
    for (int r = 0; r < 16; ++r) { s0[r] = 0.f; s1[r] = 0.f; }
#pragma unroll
    for (int ks = 0; ks < 4; ++ks) {
      s0 = MFMA32(kfA[ks], qf[ks], s0);
      s1 = MFMA32(kfB[ks], qf[ks], s1);
    }

    // tree max over the 32 locally-held scores (depth ~5, v_max3-friendly)
    float m8[8];
#pragma unroll
    for (int r = 0; r < 8; ++r)
      m8[r] = fmaxf(fmaxf(s0[r], s0[r + 8]), fmaxf(s1[r], s1[r + 8]));
    float mx = fmaxf(fmaxf(fmaxf(m8[0], m8[1]), fmaxf(m8[2], m8[3])),
                     fmaxf(fmaxf(m8[4], m8[5]), fmaxf(m8[6], m8[7])));
    mx = fmaxf(mx, pair32(mx, hi));

    // defer-max: rescale O only when max grew past THR (wave-uniform branch)
    if (!__all(mx - m_r <= 8.0f)) {
      float mnew = fmaxf(m_r, mx);
      float al = EXP2R((m_r - mnew) * C);
      m_r = mnew;
      li *= al;
      if (hi == 0) redL[w][l31] = al;    // alpha[q] at q=l31
      f32x4 a0 = *(const f32x4*)&redL[w][hi * 4];       // crow rows 8g+4hi+e
      f32x4 a1 = *(const f32x4*)&redL[w][8 + hi * 4];
      f32x4 a2 = *(const f32x4*)&redL[w][16 + hi * 4];
      f32x4 a3 = *(const f32x4*)&redL[w][24 + hi * 4];
#pragma unroll
      for (int e = 0; e < 4; ++e) {
        o0[e]      *= a0[e];  o1[e]      *= a0[e];
        o0[4 + e]  *= a1[e];  o1[4 + e]  *= a1[e];
        o0[8 + e]  *= a2[e];  o1[8 + e]  *= a2[e];
        o0[12 + e] *= a3[e];  o1[12 + e] *= a3[e];
      }
    }

    const float mC = m_r * C;
    s16x8 pa0, pa1, pa2, pa3;
    float ps0, ps1, ps2, ps3;
    SM_GRP(s0, 0, pa0, ps0);
    SM_GRP(s0, 8, pa1, ps1);
    SM_GRP(s1, 0, pa2, ps2);
    SM_GRP(s1, 8, pa3, ps3);
    float sum = (ps0 + ps1) + (ps2 + ps3);
    sum += pair32(sum, hi);
    li += sum;

    o0 = MFMA32(pa0, vfA[0], o0);  o1 = MFMA32(pa0, vfB[0], o1);
    o0 = MFMA32(pa1, vfA[1], o0);  o1 = MFMA32(pa1, vfB[1], o1);
    o0 = MFMA32(pa2, vfA[2], o0);  o1 = MFMA32(pa2, vfB[2], o1);
    o0 = MFMA32(pa3, vfA[3], o0);  o1 = MFMA32(pa3, vfB[3], o1);
  }

  // epilogue: broadcast 1/li per q, scale, store bf16
  if (hi == 0) redL[w][l31] = 1.0f / li;
  f32x4 i0 = *(const f32x4*)&redL[w][hi * 4];
  f32x4 i1 = *(const f32x4*)&redL[w][8 + hi * 4];
  f32x4 i2 = *(const f32x4*)&redL[w][16 + hi * 4];
  f32x4 i3 = *(const f32x4*)&redL[w][24 + hi * 4];

  const int p_glob = (p >> lgHG) * 16 + h0 + (p & ((1 << lgHG) - 1));
  u16* Ab = AO + (size_t)p_glob * 131072 + (size_t)q0 * 64;
#pragma unroll
  for (int g = 0; g < 4; ++g) {
    const f32x4 iv = (g == 0) ? i0 : (g == 1) ? i1 : (g == 2) ? i2 : i3;
#pragma unroll
    for (int e = 0; e < 4; ++e) {
      int row = g * 8 + hi * 4 + e;      // crow(r,hi), r = g*4+e
      Ab[(size_t)row * 64 + l31]      = f2b(o0[g * 4 + e] * iv[e]);
      Ab[(size_t)row * 64 + 32 + l31] = f2b(o1[g * 4 + e] * iv[e]);
    }
  }
}

// ---------------------------------------------------------------------------
// Kernel 3: Out(fp32) = AO @ proj_w^T + proj_b. AO bf16 at [b*16+h][t][64],
// PW bf16 from ws. r4: 64x128 tiles, grid (8,128) -> 4 blocks/CU (2x occ),
// 12 KB LDS (epilogue reuses As/Bs in 16-row slices), prefetch pipeline,
// XCD-grouped swizzle.
// ---------------------------------------------------------------------------
__global__ __launch_bounds__(256, 4) void k_proj(
    const u16* __restrict__ AO, const u16* __restrict__ W,
    const float* __restrict__ Bias, float* __restrict__ Out)
{
  __shared__ __align__(16) u16 smem[6144];    // As[2048] Bs[4096]; epi: f32[2048]
  u16* As = smem;
  u16* Bs = smem + 2048;

  const int tid = threadIdx.x;
  const int w = tid >> 6, lane = tid & 63, quad = lane >> 4, l16 = lane & 15;

  // XCD-grouped bijective swizzle (nwg = 1024): 16 M-panels x 8 N per XCD.
  const int hw = blockIdx.y * 8 + blockIdx.x;
  const int lg = (hw & 7) * 128 + (hw >> 3);
  const int m0 = (lg >> 3) * 64, n0 = (lg & 7) * 128;

  const f32x4 z4 = {0.f, 0.f, 0.f, 0.f};
  f32x4 acc[4][2];
#pragma unroll
  for (int i = 0; i < 4; ++i)
#pragma unroll
    for (int j = 0; j < 2; ++j) acc[i][j] = z4;

  const int srow = tid >> 2;                  // 0..63
  const int scol = (tid & 3) * 8;
  const int bb = m0 >> 11, tt = m0 & 2047;    // 64-row tile within one batch
  const u16* Abase = AO + (size_t)bb * 2097152 + (size_t)(tt + srow) * 64;
  const u16* Bg = W + (size_t)(n0 + srow) * 1024 + scol;

  // prologue loads (k0 = 0)
  int c0 = scol;
  s16x8 ra  = *(const s16x8*)(Abase + (size_t)(c0 >> 6) * 131072 + (c0 & 63));
  s16x8 rb0 = *(const s16x8*)(Bg);
  s16x8 rb1 = *(const s16x8*)(Bg + (size_t)64 * 1024);

  for (int k0 = 0; k0 < 1024; k0 += 32) {
    __syncthreads();
    *(s16x8*)&As[srow * 32 + scol]        = ra;
    *(s16x8*)&Bs[srow * 32 + scol]        = rb0;
    *(s16x8*)&Bs[(srow + 64) * 32 + scol] = rb1;
    __syncthreads();
    if (k0 < 992) {                       // issue next-tile loads before MFMA
      c0 = k0 + 32 + scol;
      ra  = *(const s16x8*)(Abase + (size_t)(c0 >> 6) * 131072 + (c0 & 63));
      rb0 = *(const s16x8*)(Bg + k0 + 32);
      rb1 = *(const s16x8*)(Bg + (size_t)64 * 1024 + k0 + 32);
    }
    s16x8 af[4], bf[2];
#pragma unroll
    for (int i = 0; i < 4; ++i)
      af[i] = *(const s16x8*)&As[(i * 16 + l16) * 32 + quad * 8];
#pragma unroll
    for (int j = 0; j < 2; ++j)
      bf[j] = *(const s16x8*)&Bs[(w * 32 + j * 16 + l16) * 32 + quad * 8];
#pragma unroll
    for (int i = 0; i < 4; ++i)
#pragma unroll
      for (int j = 0; j < 2; ++j)
        acc[i][j] = MFMA16(af[i], bf[j], acc[i][j]);
  }

  const int ncol = n0 + w * 32;
  float bias[2];
#pragma unroll
  for (int j = 0; j < 2; ++j) bias[j] = Bias[ncol + j * 16 + l16];

  __syncthreads();                      // all waves done with As/Bs
  float* OSw = (float*)smem + w * 512;  // per-wave 16 rows x 32 f32 (2 KB)
#pragma unroll
  for (int i = 0; i < 4; ++i) {
#pragma unroll
    for (int j = 0; j < 2; ++j)
#pragma unroll
      for (int r = 0; r < 4; ++r)
        OSw[(quad * 4 + r) * 32 + j * 16 + l16] = acc[i][j][r] + bias[j];
    // same-wave LDS ordering; wide stores: 16B/lane, 128B per 8 lanes
#pragma unroll
    for (int itr = 0; itr < 2; ++itr) {
      int task = itr * 64 + lane;
      int tl = task >> 3, g = task & 7;
      *(f32x4*)&Out[(size_t)(m0 + i * 16 + tl) * 1024 + ncol + g * 4] =
          *(const f32x4*)&OSw[tl * 32 + g * 4];
    }
  }
}

// ---------------------------------------------------------------------------
extern "C" void kernel_launch(void* const* d_in, const int* in_sizes, int n_in,
                              void* d_out, int out_size, void* d_ws, size_t ws_size,
                              hipStream_t stream) {
  const float* X    = (const float*)d_in[0];   // [4,2048,1024] fp32
  const float* QKVW = (const float*)d_in[1];   // [3072,1024]
  const float* QKVB = (const float*)d_in[2];   // [3072]
  const float* PW   = (const float*)d_in[3];   // [1024,1024]
  const float* PB   = (const float*)d_in[4];   // [1024]
  float* Out = (float*)d_out;                  // [4,2048,1024] fp32
  u16* ws = (u16*)d_ws;

  // ws (bytes): HG16: 2*(PWOFF+3*segE)=52.4MB (AO aliases Qc);
  // HG<16: + dedicated AO (16.8MB).
  int HG, lgHG, ok = 1;
  if      (ws_size >= 52428800ull) { HG = 16; lgHG = 4; }
  else if (ws_size >= 44040192ull) { HG = 8;  lgHG = 3; }
  else if (ws_size >= 31457280ull) { HG = 4;  lgHG = 2; }
  else if (ws_size >= 25165824ull) { HG = 2;  lgHG = 1; }
  else                             { HG = 2;  lgHG = 1; ok = 0; }

  if (!ok) {
    k_beacon<<<dim3(4096), 256, 0, stream>>>(Out, (unsigned long long)ws_size);
    return;
  }

  const size_t segE = 524288ull << lgHG;
  u16* Qc = ws + PWOFF;
  u16* AO = (HG == 16) ? Qc : (Qc + 3 * segE);
  const int lgHB = lgHG + 6;

  k_convert_pw<<<dim3(512), 256, 0, stream>>>(PW, ws);

  const int chunks = 16 / HG;
  for (int c = 0; c < chunks; ++c) {
    int h0 = c * HG;
    k_qkv_rope<<<dim3((3 * HG) / 2, 64), 256, 0, stream>>>(
        X, QKVW, QKVB, ws, h0, lgHB, lgHG);
    k_attn<<<dim3(16, 4 * HG), 256, 0, stream>>>(ws, AO, h0, lgHG);
  }
  k_proj<<<dim3(8, 128), 256, 0, stream>>>(AO, ws, PB, Out);
}